// Round 1
// baseline (1007.939 us; speedup 1.0000x reference)
//
#include <hip/hip_runtime.h>
#include <hip/hip_bf16.h>

#define N_NODES 20000
#define IN_DIM 128
#define HID 256
#define OUT_DIM 10
#define N_EDGES 320000
#define N_GRAPHS 64

// ---------------------------------------------------------------------------
// vectorized copy: dst = src (float4 grid-stride)
__global__ void copy_f32(const float* __restrict__ src, float* __restrict__ dst, int n4) {
    int i = blockIdx.x * blockDim.x + threadIdx.x;
    int stride = gridDim.x * blockDim.x;
    for (; i < n4; i += stride) {
        reinterpret_cast<float4*>(dst)[i] = reinterpret_cast<const float4*>(src)[i];
    }
}

// ---------------------------------------------------------------------------
// scatter-add: out[dst[e]*D + d] += x[src[e]*D + d]   (one thread per (e,d))
__global__ void scatter_add(const float* __restrict__ x, float* __restrict__ out,
                            const int* __restrict__ src, const int* __restrict__ dst,
                            int total, int logD) {
    int i = blockIdx.x * blockDim.x + threadIdx.x;
    int stride = gridDim.x * blockDim.x;
    int dmask = (1 << logD) - 1;
    for (; i < total; i += stride) {
        int e = i >> logD;
        int d = i & dmask;
        int s = src[e];
        int t = dst[e];
        atomicAdd(&out[((long long)t << logD) + d], x[((long long)s << logD) + d]);
    }
}

// ---------------------------------------------------------------------------
// C = relu(A @ B + bias), A: MxK row-major, B: KxN row-major, C: MxN
// BM=BN=64, BK=16, 256 threads, 4x4 micro-tile per thread.
#define BM 64
#define BN 64
#define BK 16

__global__ __launch_bounds__(256) void gemm_bias_relu(
    const float* __restrict__ A, const float* __restrict__ B,
    const float* __restrict__ bias, float* __restrict__ C,
    int M, int K, int N, int do_relu)
{
    __shared__ float As[BK][BM];
    __shared__ float Bs[BK][BN];

    int tid = threadIdx.x;
    int tx = tid & 15;        // 0..15 -> col group
    int ty = tid >> 4;        // 0..15 -> row group
    int m0 = blockIdx.x * BM;
    int n0 = blockIdx.y * BN;

    float acc[4][4] = {};

    int lr = tid >> 2;        // 0..63 : A-tile row
    int lk = (tid & 3) * 4;   // 0,4,8,12 : A-tile k offset
    int brow = tid >> 4;      // 0..15 : B-tile row
    int bcol = (tid & 15) * 4;// B-tile col offset

    for (int k0 = 0; k0 < K; k0 += BK) {
        float4 a4;
        int arow = m0 + lr;
        if (arow < M) {
            a4 = *reinterpret_cast<const float4*>(&A[(long long)arow * K + k0 + lk]);
        } else {
            a4 = make_float4(0.f, 0.f, 0.f, 0.f);
        }
        As[lk + 0][lr] = a4.x;
        As[lk + 1][lr] = a4.y;
        As[lk + 2][lr] = a4.z;
        As[lk + 3][lr] = a4.w;

        float4 b4 = *reinterpret_cast<const float4*>(&B[(long long)(k0 + brow) * N + n0 + bcol]);
        *reinterpret_cast<float4*>(&Bs[brow][bcol]) = b4;

        __syncthreads();
        #pragma unroll
        for (int k = 0; k < BK; ++k) {
            float4 av = *reinterpret_cast<const float4*>(&As[k][ty * 4]);
            float4 bv = *reinterpret_cast<const float4*>(&Bs[k][tx * 4]);
            float a[4] = {av.x, av.y, av.z, av.w};
            float b[4] = {bv.x, bv.y, bv.z, bv.w};
            #pragma unroll
            for (int i = 0; i < 4; ++i)
                #pragma unroll
                for (int j = 0; j < 4; ++j)
                    acc[i][j] += a[i] * b[j];
        }
        __syncthreads();
    }

    #pragma unroll
    for (int i = 0; i < 4; ++i) {
        int row = m0 + ty * 4 + i;
        if (row >= M) continue;
        int col0 = n0 + tx * 4;
        float4 v;
        float* vp = &v.x;
        #pragma unroll
        for (int j = 0; j < 4; ++j) {
            float t = acc[i][j] + bias[col0 + j];
            if (do_relu) t = fmaxf(t, 0.f);
            vp[j] = t;
        }
        *reinterpret_cast<float4*>(&C[(long long)row * N + col0]) = v;
    }
}

// ---------------------------------------------------------------------------
// fused pooling (segment-sum over sorted batch) + head GEMM + log_softmax
__global__ __launch_bounds__(256) void pool_head(
    const float* __restrict__ h, const int* __restrict__ batch,
    const float* __restrict__ wl, const float* __restrict__ bl,
    float* __restrict__ out, int n_nodes)
{
    int g = blockIdx.x;      // graph id
    int d = threadIdx.x;     // 0..255 : hidden dim

    // lower_bound(batch, g) and lower_bound(batch, g+1)
    int lo = 0, hi = n_nodes;
    while (lo < hi) { int mid = (lo + hi) >> 1; if (batch[mid] < g) lo = mid + 1; else hi = mid; }
    int s = lo;
    lo = 0; hi = n_nodes;
    while (lo < hi) { int mid = (lo + hi) >> 1; if (batch[mid] < g + 1) lo = mid + 1; else hi = mid; }
    int e = lo;

    float acc = 0.f;
    for (int n = s; n < e; ++n) acc += h[(long long)n * HID + d];

    __shared__ float pooled[HID];
    __shared__ float logits[OUT_DIM];
    __shared__ float lse_s;
    pooled[d] = acc;
    __syncthreads();

    if (d < OUT_DIM) {
        float v = bl[d];
        for (int k = 0; k < HID; ++k) v += pooled[k] * wl[k * OUT_DIM + d];
        logits[d] = v;
    }
    __syncthreads();

    if (d == 0) {
        float mx = logits[0];
        for (int j = 1; j < OUT_DIM; ++j) mx = fmaxf(mx, logits[j]);
        float ssum = 0.f;
        for (int j = 0; j < OUT_DIM; ++j) ssum += expf(logits[j] - mx);
        lse_s = mx + logf(ssum);
    }
    __syncthreads();

    if (d < OUT_DIM) out[g * OUT_DIM + d] = logits[d] - lse_s;
}

// ---------------------------------------------------------------------------
extern "C" void kernel_launch(void* const* d_in, const int* in_sizes, int n_in,
                              void* d_out, int out_size, void* d_ws, size_t ws_size,
                              hipStream_t stream) {
    const float* x    = (const float*)d_in[0];
    const int*   ei   = (const int*)d_in[1];
    const int*   batch= (const int*)d_in[2];
    const float* w1a  = (const float*)d_in[3];
    const float* b1a  = (const float*)d_in[4];
    const float* w1b  = (const float*)d_in[5];
    const float* b1b  = (const float*)d_in[6];
    const float* w2a  = (const float*)d_in[7];
    const float* b2a  = (const float*)d_in[8];
    const float* w2b  = (const float*)d_in[9];
    const float* b2b  = (const float*)d_in[10];
    const float* w3a  = (const float*)d_in[11];
    const float* b3a  = (const float*)d_in[12];
    const float* w3b  = (const float*)d_in[13];
    const float* b3b  = (const float*)d_in[14];
    const float* wl   = (const float*)d_in[15];
    const float* bl   = (const float*)d_in[16];

    const int* src = ei;
    const int* dst = ei + N_EDGES;

    float* bufA = (float*)d_ws;                       // 20000*256
    float* bufB = bufA + (size_t)N_NODES * HID;       // 20000*256
    float* bufC = bufB + (size_t)N_NODES * HID;       // 20000*256

    float* out = (float*)d_out;

    dim3 gemm_grid((N_NODES + BM - 1) / BM, HID / BN);

    // ---- layer 1 (input dim 128) ----
    {
        int n4 = N_NODES * IN_DIM / 4;
        copy_f32<<<(n4 + 255) / 256, 256, 0, stream>>>(x, bufC, n4);
        int total = N_EDGES * IN_DIM;
        scatter_add<<<(total + 255) / 256, 256, 0, stream>>>(x, bufC, src, dst, total, 7);
        gemm_bias_relu<<<gemm_grid, 256, 0, stream>>>(bufC, w1a, b1a, bufB, N_NODES, IN_DIM, HID, 1);
        gemm_bias_relu<<<gemm_grid, 256, 0, stream>>>(bufB, w1b, b1b, bufA, N_NODES, HID, HID, 1);
    }
    // ---- layers 2,3 (dim 256) ----
    const float* wa[2] = {w2a, w3a};
    const float* ba[2] = {b2a, b3a};
    const float* wb[2] = {w2b, w3b};
    const float* bb[2] = {b2b, b3b};
    for (int l = 0; l < 2; ++l) {
        int n4 = N_NODES * HID / 4;
        copy_f32<<<(n4 + 255) / 256, 256, 0, stream>>>(bufA, bufC, n4);
        int total = N_EDGES * HID;
        scatter_add<<<(total + 255) / 256, 256, 0, stream>>>(bufA, bufC, src, dst, total, 8);
        gemm_bias_relu<<<gemm_grid, 256, 0, stream>>>(bufC, wa[l], ba[l], bufB, N_NODES, HID, HID, 1);
        gemm_bias_relu<<<gemm_grid, 256, 0, stream>>>(bufB, wb[l], bb[l], bufA, N_NODES, HID, HID, 1);
    }

    // ---- pool + head + log_softmax ----
    pool_head<<<N_GRAPHS, 256, 0, stream>>>(bufA, batch, wl, bl, out, N_NODES);
}

// Round 2
// 535.675 us; speedup vs baseline: 1.8816x; 1.8816x over previous
//
#include <hip/hip_runtime.h>
#include <hip/hip_bf16.h>

#define N_NODES 20000
#define IN_DIM 128
#define HID 256
#define OUT_DIM 10
#define N_EDGES 320000
#define N_GRAPHS 64

// ---------------------------------------------------------------------------
// CSR build: zero degrees
__global__ void zero_int(int* __restrict__ p, int n) {
    int i = blockIdx.x * blockDim.x + threadIdx.x;
    if (i < n) p[i] = 0;
}

// histogram of dst
__global__ void degree_hist(const int* __restrict__ dst, int* __restrict__ deg, int n) {
    int i = blockIdx.x * blockDim.x + threadIdx.x;
    int stride = gridDim.x * blockDim.x;
    for (; i < n; i += stride) atomicAdd(&deg[dst[i]], 1);
}

// single-block exclusive scan over deg[0..n) -> row_ptr[0..n], pos copy
__global__ __launch_bounds__(1024) void scan_deg(const int* __restrict__ deg,
                                                 int* __restrict__ row_ptr,
                                                 int* __restrict__ pos, int n) {
    __shared__ int sums[1024];
    int tid = threadIdx.x;
    int chunk = (n + 1023) / 1024;
    int base = tid * chunk;
    int s = 0;
    for (int i = 0; i < chunk; ++i) {
        int idx = base + i;
        if (idx < n) s += deg[idx];
    }
    sums[tid] = s;
    __syncthreads();
    for (int off = 1; off < 1024; off <<= 1) {
        int v = (tid >= off) ? sums[tid - off] : 0;
        __syncthreads();
        if (tid >= off) sums[tid] += v;
        __syncthreads();
    }
    int run = (tid == 0) ? 0 : sums[tid - 1];
    for (int i = 0; i < chunk; ++i) {
        int idx = base + i;
        if (idx < n) {
            row_ptr[idx] = run;
            pos[idx] = run;
            run += deg[idx];
            if (idx == n - 1) row_ptr[n] = run;
        }
    }
}

// fill col: for each edge, slot = pos[dst]++; col[slot] = src
__global__ void csr_fill(const int* __restrict__ src, const int* __restrict__ dst,
                         int* __restrict__ pos, int* __restrict__ col, int n) {
    int i = blockIdx.x * blockDim.x + threadIdx.x;
    int stride = gridDim.x * blockDim.x;
    for (; i < n; i += stride) {
        int slot = atomicAdd(&pos[dst[i]], 1);
        col[slot] = src[i];
    }
}

// ---------------------------------------------------------------------------
// gather-aggregate: out[i] = x[i] + sum_{j in in-edges(i)} x[j]
// one wave (64 lanes) per node; lane handles D/64 consecutive floats
template <int D>
__global__ __launch_bounds__(256) void gin_aggregate(
    const float* __restrict__ x, const int* __restrict__ row_ptr,
    const int* __restrict__ col, float* __restrict__ out)
{
    constexpr int PER = D / 64;  // 4 (D=256) or 2 (D=128)
    int node = blockIdx.x * 4 + (threadIdx.x >> 6);
    if (node >= N_NODES) return;
    int lane = threadIdx.x & 63;
    size_t off = (size_t)node * D + lane * PER;

    float acc[PER];
    if constexpr (PER == 4) {
        float4 v = *reinterpret_cast<const float4*>(x + off);
        acc[0] = v.x; acc[1] = v.y; acc[2] = v.z; acc[3] = v.w;
    } else {
        float2 v = *reinterpret_cast<const float2*>(x + off);
        acc[0] = v.x; acc[1] = v.y;
    }

    int s = row_ptr[node], e = row_ptr[node + 1];
    for (int k = s; k < e; ++k) {
        int c = col[k];
        const float* p = x + (size_t)c * D + lane * PER;
        if constexpr (PER == 4) {
            float4 v = *reinterpret_cast<const float4*>(p);
            acc[0] += v.x; acc[1] += v.y; acc[2] += v.z; acc[3] += v.w;
        } else {
            float2 v = *reinterpret_cast<const float2*>(p);
            acc[0] += v.x; acc[1] += v.y;
        }
    }

    if constexpr (PER == 4) {
        float4 v = make_float4(acc[0], acc[1], acc[2], acc[3]);
        *reinterpret_cast<float4*>(out + off) = v;
    } else {
        float2 v = make_float2(acc[0], acc[1]);
        *reinterpret_cast<float2*>(out + off) = v;
    }
}

// ---------------------------------------------------------------------------
// C = relu(A @ B + bias), A: MxK row-major, B: KxN row-major, C: MxN
#define BM 64
#define BN 64
#define BK 16

__global__ __launch_bounds__(256) void gemm_bias_relu(
    const float* __restrict__ A, const float* __restrict__ B,
    const float* __restrict__ bias, float* __restrict__ C,
    int M, int K, int N, int do_relu)
{
    __shared__ float As[BK][BM];
    __shared__ float Bs[BK][BN];

    int tid = threadIdx.x;
    int tx = tid & 15;
    int ty = tid >> 4;
    int m0 = blockIdx.x * BM;
    int n0 = blockIdx.y * BN;

    float acc[4][4] = {};

    int lr = tid >> 2;
    int lk = (tid & 3) * 4;
    int brow = tid >> 4;
    int bcol = (tid & 15) * 4;

    for (int k0 = 0; k0 < K; k0 += BK) {
        float4 a4;
        int arow = m0 + lr;
        if (arow < M) {
            a4 = *reinterpret_cast<const float4*>(&A[(long long)arow * K + k0 + lk]);
        } else {
            a4 = make_float4(0.f, 0.f, 0.f, 0.f);
        }
        As[lk + 0][lr] = a4.x;
        As[lk + 1][lr] = a4.y;
        As[lk + 2][lr] = a4.z;
        As[lk + 3][lr] = a4.w;

        float4 b4 = *reinterpret_cast<const float4*>(&B[(long long)(k0 + brow) * N + n0 + bcol]);
        *reinterpret_cast<float4*>(&Bs[brow][bcol]) = b4;

        __syncthreads();
        #pragma unroll
        for (int k = 0; k < BK; ++k) {
            float4 av = *reinterpret_cast<const float4*>(&As[k][ty * 4]);
            float4 bv = *reinterpret_cast<const float4*>(&Bs[k][tx * 4]);
            float a[4] = {av.x, av.y, av.z, av.w};
            float b[4] = {bv.x, bv.y, bv.z, bv.w};
            #pragma unroll
            for (int i = 0; i < 4; ++i)
                #pragma unroll
                for (int j = 0; j < 4; ++j)
                    acc[i][j] += a[i] * b[j];
        }
        __syncthreads();
    }

    #pragma unroll
    for (int i = 0; i < 4; ++i) {
        int row = m0 + ty * 4 + i;
        if (row >= M) continue;
        int col0 = n0 + tx * 4;
        float4 v;
        float* vp = &v.x;
        #pragma unroll
        for (int j = 0; j < 4; ++j) {
            float t = acc[i][j] + bias[col0 + j];
            if (do_relu) t = fmaxf(t, 0.f);
            vp[j] = t;
        }
        *reinterpret_cast<float4*>(&C[(long long)row * N + col0]) = v;
    }
}

// ---------------------------------------------------------------------------
// fused pooling (segment-sum over sorted batch) + head GEMM + log_softmax
__global__ __launch_bounds__(256) void pool_head(
    const float* __restrict__ h, const int* __restrict__ batch,
    const float* __restrict__ wl, const float* __restrict__ bl,
    float* __restrict__ out, int n_nodes)
{
    int g = blockIdx.x;
    int d = threadIdx.x;

    int lo = 0, hi = n_nodes;
    while (lo < hi) { int mid = (lo + hi) >> 1; if (batch[mid] < g) lo = mid + 1; else hi = mid; }
    int s = lo;
    lo = 0; hi = n_nodes;
    while (lo < hi) { int mid = (lo + hi) >> 1; if (batch[mid] < g + 1) lo = mid + 1; else hi = mid; }
    int e = lo;

    float acc = 0.f;
    for (int n = s; n < e; ++n) acc += h[(long long)n * HID + d];

    __shared__ float pooled[HID];
    __shared__ float logits[OUT_DIM];
    __shared__ float lse_s;
    pooled[d] = acc;
    __syncthreads();

    if (d < OUT_DIM) {
        float v = bl[d];
        for (int k = 0; k < HID; ++k) v += pooled[k] * wl[k * OUT_DIM + d];
        logits[d] = v;
    }
    __syncthreads();

    if (d == 0) {
        float mx = logits[0];
        for (int j = 1; j < OUT_DIM; ++j) mx = fmaxf(mx, logits[j]);
        float ssum = 0.f;
        for (int j = 0; j < OUT_DIM; ++j) ssum += expf(logits[j] - mx);
        lse_s = mx + logf(ssum);
    }
    __syncthreads();

    if (d < OUT_DIM) out[g * OUT_DIM + d] = logits[d] - lse_s;
}

// ---------------------------------------------------------------------------
extern "C" void kernel_launch(void* const* d_in, const int* in_sizes, int n_in,
                              void* d_out, int out_size, void* d_ws, size_t ws_size,
                              hipStream_t stream) {
    const float* x    = (const float*)d_in[0];
    const int*   ei   = (const int*)d_in[1];
    const int*   batch= (const int*)d_in[2];
    const float* w1a  = (const float*)d_in[3];
    const float* b1a  = (const float*)d_in[4];
    const float* w1b  = (const float*)d_in[5];
    const float* b1b  = (const float*)d_in[6];
    const float* w2a  = (const float*)d_in[7];
    const float* b2a  = (const float*)d_in[8];
    const float* w2b  = (const float*)d_in[9];
    const float* b2b  = (const float*)d_in[10];
    const float* w3a  = (const float*)d_in[11];
    const float* b3a  = (const float*)d_in[12];
    const float* w3b  = (const float*)d_in[13];
    const float* b3b  = (const float*)d_in[14];
    const float* wl   = (const float*)d_in[15];
    const float* bl   = (const float*)d_in[16];

    const int* src = ei;
    const int* dst = ei + N_EDGES;

    float* bufA = (float*)d_ws;                        // 20000*256 f32
    float* bufB = bufA + (size_t)N_NODES * HID;        // 20000*256 f32
    int* deg     = (int*)(bufB + (size_t)N_NODES * HID);
    int* row_ptr = deg + N_NODES;                      // N_NODES+1
    int* pos     = row_ptr + (N_NODES + 1);
    int* col     = pos + N_NODES;                      // N_EDGES

    float* out = (float*)d_out;

    // ---- build CSR (by destination) ----
    zero_int<<<(N_NODES + 255) / 256, 256, 0, stream>>>(deg, N_NODES);
    degree_hist<<<(N_EDGES + 255) / 256, 256, 0, stream>>>(dst, deg, N_EDGES);
    scan_deg<<<1, 1024, 0, stream>>>(deg, row_ptr, pos, N_NODES);
    csr_fill<<<(N_EDGES + 255) / 256, 256, 0, stream>>>(src, dst, pos, col, N_EDGES);

    dim3 gemm_grid((N_NODES + BM - 1) / BM, HID / BN);
    int agg_blocks = (N_NODES + 3) / 4;

    // ---- layer 1 (input dim 128) ----
    gin_aggregate<IN_DIM><<<agg_blocks, 256, 0, stream>>>(x, row_ptr, col, bufA);
    gemm_bias_relu<<<gemm_grid, 256, 0, stream>>>(bufA, w1a, b1a, bufB, N_NODES, IN_DIM, HID, 1);
    gemm_bias_relu<<<gemm_grid, 256, 0, stream>>>(bufB, w1b, b1b, bufA, N_NODES, HID, HID, 1);

    // ---- layer 2 ----
    gin_aggregate<HID><<<agg_blocks, 256, 0, stream>>>(bufA, row_ptr, col, bufB);
    gemm_bias_relu<<<gemm_grid, 256, 0, stream>>>(bufB, w2a, b2a, bufA, N_NODES, HID, HID, 1);
    gemm_bias_relu<<<gemm_grid, 256, 0, stream>>>(bufA, w2b, b2b, bufB, N_NODES, HID, HID, 1);

    // ---- layer 3 ----
    gin_aggregate<HID><<<agg_blocks, 256, 0, stream>>>(bufB, row_ptr, col, bufA);
    gemm_bias_relu<<<gemm_grid, 256, 0, stream>>>(bufA, w3a, b3a, bufB, N_NODES, HID, HID, 1);
    gemm_bias_relu<<<gemm_grid, 256, 0, stream>>>(bufB, w3b, b3b, bufA, N_NODES, HID, HID, 1);

    // ---- pool + head + log_softmax ----
    pool_head<<<N_GRAPHS, 256, 0, stream>>>(bufA, batch, wl, bl, out, N_NODES);
}

// Round 3
// 331.561 us; speedup vs baseline: 3.0400x; 1.6156x over previous
//
#include <hip/hip_runtime.h>
#include <hip/hip_bf16.h>

#define N_NODES 20000
#define M_PAD 20096            // 157 * 128
#define IN_DIM 128
#define HID 256
#define OUT_DIM 10
#define N_EDGES 320000
#define N_GRAPHS 64

typedef __attribute__((ext_vector_type(8))) short bf16x8;
typedef __attribute__((ext_vector_type(4))) float f32x4;

__device__ inline float bf2f(unsigned short u) {
    return __uint_as_float((unsigned int)u << 16);
}
__device__ inline unsigned short f2bf(float f) {
    __hip_bfloat16 h = __float2bfloat16(f);
    return *reinterpret_cast<unsigned short*>(&h);
}

// ---------------------------------------------------------------------------
// CSR build
__global__ void zero_int(int* __restrict__ p, int n) {
    int i = blockIdx.x * blockDim.x + threadIdx.x;
    if (i < n) p[i] = 0;
}

__global__ void degree_hist(const int* __restrict__ dst, int* __restrict__ deg, int n) {
    int i = blockIdx.x * blockDim.x + threadIdx.x;
    int stride = gridDim.x * blockDim.x;
    for (; i < n; i += stride) atomicAdd(&deg[dst[i]], 1);
}

__global__ __launch_bounds__(1024) void scan_deg(const int* __restrict__ deg,
                                                 int* __restrict__ row_ptr,
                                                 int* __restrict__ pos, int n) {
    __shared__ int sums[1024];
    int tid = threadIdx.x;
    int chunk = (n + 1023) / 1024;
    int base = tid * chunk;
    int s = 0;
    for (int i = 0; i < chunk; ++i) {
        int idx = base + i;
        if (idx < n) s += deg[idx];
    }
    sums[tid] = s;
    __syncthreads();
    for (int off = 1; off < 1024; off <<= 1) {
        int v = (tid >= off) ? sums[tid - off] : 0;
        __syncthreads();
        if (tid >= off) sums[tid] += v;
        __syncthreads();
    }
    int run = (tid == 0) ? 0 : sums[tid - 1];
    for (int i = 0; i < chunk; ++i) {
        int idx = base + i;
        if (idx < n) {
            row_ptr[idx] = run;
            pos[idx] = run;
            run += deg[idx];
            if (idx == n - 1) row_ptr[n] = run;
        }
    }
}

__global__ void csr_fill(const int* __restrict__ src, const int* __restrict__ dst,
                         int* __restrict__ pos, int* __restrict__ col, int n) {
    int i = blockIdx.x * blockDim.x + threadIdx.x;
    int stride = gridDim.x * blockDim.x;
    for (; i < n; i += stride) {
        int slot = atomicAdd(&pos[dst[i]], 1);
        col[slot] = src[i];
    }
}

// ---------------------------------------------------------------------------
// weight transpose + convert: in[rows][cols] f32 -> out[cols][rows] bf16
__global__ __launch_bounds__(256) void transpose_to_bf16(
    const float* __restrict__ in, __hip_bfloat16* __restrict__ out,
    int rows, int cols)
{
    __shared__ float tile[32][33];
    int c0 = blockIdx.x * 32, r0 = blockIdx.y * 32;
    int tx = threadIdx.x & 31, ty = threadIdx.x >> 5;  // 32 x 8
    for (int i = ty; i < 32; i += 8) {
        int r = r0 + i, c = c0 + tx;
        tile[i][tx] = (r < rows && c < cols) ? in[(size_t)r * cols + c] : 0.f;
    }
    __syncthreads();
    for (int i = ty; i < 32; i += 8) {
        int c = c0 + i, r = r0 + tx;   // write out[c][r]
        if (c < cols && r < rows) out[(size_t)c * rows + r] = __float2bfloat16(tile[tx][i]);
    }
}

// ---------------------------------------------------------------------------
// layer-1 aggregate: f32 in [N_NODES][128] -> bf16 out [M_PAD][128]
__global__ __launch_bounds__(256) void gin_agg_l1(
    const float* __restrict__ x, const int* __restrict__ row_ptr,
    const int* __restrict__ col, __hip_bfloat16* __restrict__ out)
{
    int node = blockIdx.x * 4 + (threadIdx.x >> 6);
    if (node >= N_NODES) return;
    int lane = threadIdx.x & 63;
    int off = lane * 2;
    float2 a = *reinterpret_cast<const float2*>(x + (size_t)node * IN_DIM + off);
    int s = row_ptr[node], e = row_ptr[node + 1];
    for (int k = s; k < e; ++k) {
        float2 v = *reinterpret_cast<const float2*>(x + (size_t)col[k] * IN_DIM + off);
        a.x += v.x; a.y += v.y;
    }
    ushort2 o;
    o.x = f2bf(a.x); o.y = f2bf(a.y);
    *reinterpret_cast<ushort2*>(out + (size_t)node * IN_DIM + off) = o;
}

// bf16 aggregate: bf16 in [M_PAD][256] -> bf16 out [M_PAD][256] (rows < N_NODES)
__global__ __launch_bounds__(256) void gin_agg_bf16(
    const __hip_bfloat16* __restrict__ x, const int* __restrict__ row_ptr,
    const int* __restrict__ col, __hip_bfloat16* __restrict__ out)
{
    int node = blockIdx.x * 4 + (threadIdx.x >> 6);
    if (node >= N_NODES) return;
    int lane = threadIdx.x & 63;
    int off = lane * 4;
    float acc[4];
    ushort4 v = *reinterpret_cast<const ushort4*>(x + (size_t)node * HID + off);
    acc[0] = bf2f(v.x); acc[1] = bf2f(v.y); acc[2] = bf2f(v.z); acc[3] = bf2f(v.w);
    int s = row_ptr[node], e = row_ptr[node + 1];
    for (int k = s; k < e; ++k) {
        ushort4 u = *reinterpret_cast<const ushort4*>(x + (size_t)col[k] * HID + off);
        acc[0] += bf2f(u.x); acc[1] += bf2f(u.y); acc[2] += bf2f(u.z); acc[3] += bf2f(u.w);
    }
    ushort4 o;
    o.x = f2bf(acc[0]); o.y = f2bf(acc[1]); o.z = f2bf(acc[2]); o.w = f2bf(acc[3]);
    *reinterpret_cast<ushort4*>(out + (size_t)node * HID + off) = o;
}

// ---------------------------------------------------------------------------
// bf16 MFMA GEMM: C[M_PAD][256] = relu(A[M_PAD][K] @ Wt[256][K]^T + bias)
// 128x128 tile, BK=32, 4 waves (2x2), each wave 64x64 (4x4 fragments 16x16).
// LDS tiles stored [dim][k] with 16B-granule XOR swizzle: g ^= (row>>1)&3.
template<int K>
__global__ __launch_bounds__(256) void gemm_bf16(
    const __hip_bfloat16* __restrict__ A, const __hip_bfloat16* __restrict__ Wt,
    const float* __restrict__ bias, __hip_bfloat16* __restrict__ C)
{
    constexpr int BM = 128;
    __shared__ int4 As4[512];   // 128 rows * 64B
    __shared__ int4 Bs4[512];
    char* As = (char*)As4;
    char* Bs = (char*)Bs4;

    int tid = threadIdx.x;
    int lane = tid & 63;
    int wid = tid >> 6;
    int wr = wid >> 1, wc = wid & 1;
    int m0 = blockIdx.x * BM;
    int n0 = blockIdx.y * BM;

    f32x4 acc[4][4] = {};

    int srow = tid >> 2;     // 0..63
    int sg   = tid & 3;      // 16B chunk within 64B row

    int g = lane >> 4;       // k-group for fragment reads
    int r16 = lane & 15;

    #pragma unroll 1
    for (int k0 = 0; k0 < K; k0 += 32) {
        #pragma unroll
        for (int h = 0; h < 2; ++h) {
            int r = srow + h * 64;
            int swz = (sg ^ ((r >> 1) & 3)) * 16;
            int4 va = *reinterpret_cast<const int4*>(A + (size_t)(m0 + r) * K + k0 + sg * 8);
            *reinterpret_cast<int4*>(As + r * 64 + swz) = va;
            int4 vb = *reinterpret_cast<const int4*>(Wt + (size_t)(n0 + r) * K + k0 + sg * 8);
            *reinterpret_cast<int4*>(Bs + r * 64 + swz) = vb;
        }
        __syncthreads();

        bf16x8 af[4], bfr[4];
        #pragma unroll
        for (int m = 0; m < 4; ++m) {
            int row = wr * 64 + m * 16 + r16;
            int gg = g ^ ((row >> 1) & 3);
            af[m] = *reinterpret_cast<const bf16x8*>(As + row * 64 + gg * 16);
        }
        #pragma unroll
        for (int n = 0; n < 4; ++n) {
            int row = wc * 64 + n * 16 + r16;
            int gg = g ^ ((row >> 1) & 3);
            bfr[n] = *reinterpret_cast<const bf16x8*>(Bs + row * 64 + gg * 16);
        }
        #pragma unroll
        for (int m = 0; m < 4; ++m)
            #pragma unroll
            for (int n = 0; n < 4; ++n)
                acc[m][n] = __builtin_amdgcn_mfma_f32_16x16x32_bf16(af[m], bfr[n], acc[m][n], 0, 0, 0);
        __syncthreads();
    }

    // epilogue: bias + relu + bf16 store.  C/D: col=lane&15, row=(lane>>4)*4+reg
    float bv[4];
    #pragma unroll
    for (int n = 0; n < 4; ++n) bv[n] = bias[n0 + wc * 64 + n * 16 + r16];

    #pragma unroll
    for (int m = 0; m < 4; ++m) {
        #pragma unroll
        for (int n = 0; n < 4; ++n) {
            int col = n0 + wc * 64 + n * 16 + r16;
            #pragma unroll
            for (int r = 0; r < 4; ++r) {
                int row = m0 + wr * 64 + m * 16 + (lane >> 4) * 4 + r;
                float v = acc[m][n][r] + bv[n];
                v = fmaxf(v, 0.f);
                C[(size_t)row * HID + col] = __float2bfloat16(v);
            }
        }
    }
}

// ---------------------------------------------------------------------------
// pooling: 157 blocks x 128 nodes, per-thread register acc, atomic flush at
// graph boundaries (batch sorted). pooled must be zeroed first.
__global__ __launch_bounds__(256) void pool_partial(
    const __hip_bfloat16* __restrict__ h, const int* __restrict__ batch,
    float* __restrict__ pooled)
{
    __shared__ int sb[128];
    int n0 = blockIdx.x * 128;
    int cnt = N_NODES - n0; if (cnt > 128) cnt = 128;
    int d = threadIdx.x;
    if (d < cnt) sb[d] = batch[n0 + d];
    __syncthreads();
    float acc = 0.f;
    int cur = sb[0];
    for (int i = 0; i < cnt; ++i) {
        int g = sb[i];
        if (g != cur) { atomicAdd(&pooled[cur * HID + d], acc); acc = 0.f; cur = g; }
        acc += bf2f(*reinterpret_cast<const unsigned short*>(h + (size_t)(n0 + i) * HID + d));
    }
    atomicAdd(&pooled[cur * HID + d], acc);
}

// head: logits = pooled @ wl + bl ; log_softmax
__global__ __launch_bounds__(256) void head_kernel(
    const float* __restrict__ pooled, const float* __restrict__ wl,
    const float* __restrict__ bl, float* __restrict__ out)
{
    int gph = blockIdx.x;
    int d = threadIdx.x;
    __shared__ float p[HID];
    __shared__ float logits[OUT_DIM];
    __shared__ float lse_s;
    p[d] = pooled[gph * HID + d];
    __syncthreads();
    if (d < OUT_DIM) {
        float v = bl[d];
        for (int k = 0; k < HID; ++k) v += p[k] * wl[k * OUT_DIM + d];
        logits[d] = v;
    }
    __syncthreads();
    if (d == 0) {
        float mx = logits[0];
        for (int j = 1; j < OUT_DIM; ++j) mx = fmaxf(mx, logits[j]);
        float s = 0.f;
        for (int j = 0; j < OUT_DIM; ++j) s += expf(logits[j] - mx);
        lse_s = mx + logf(s);
    }
    __syncthreads();
    if (d < OUT_DIM) out[gph * OUT_DIM + d] = logits[d] - lse_s;
}

// ---------------------------------------------------------------------------
extern "C" void kernel_launch(void* const* d_in, const int* in_sizes, int n_in,
                              void* d_out, int out_size, void* d_ws, size_t ws_size,
                              hipStream_t stream) {
    const float* x    = (const float*)d_in[0];
    const int*   ei   = (const int*)d_in[1];
    const int*   batch= (const int*)d_in[2];
    const float* w1a  = (const float*)d_in[3];
    const float* b1a  = (const float*)d_in[4];
    const float* w1b  = (const float*)d_in[5];
    const float* b1b  = (const float*)d_in[6];
    const float* w2a  = (const float*)d_in[7];
    const float* b2a  = (const float*)d_in[8];
    const float* w2b  = (const float*)d_in[9];
    const float* b2b  = (const float*)d_in[10];
    const float* w3a  = (const float*)d_in[11];
    const float* b3a  = (const float*)d_in[12];
    const float* w3b  = (const float*)d_in[13];
    const float* b3b  = (const float*)d_in[14];
    const float* wl   = (const float*)d_in[15];
    const float* bl   = (const float*)d_in[16];

    const int* src = ei;
    const int* dst = ei + N_EDGES;

    // workspace layout (all 16B aligned)
    __hip_bfloat16* bufA = (__hip_bfloat16*)d_ws;                  // M_PAD*256
    __hip_bfloat16* bufB = bufA + (size_t)M_PAD * HID;             // M_PAD*256
    __hip_bfloat16* wt1a = bufB + (size_t)M_PAD * HID;             // 256*128
    __hip_bfloat16* wt1b = wt1a + HID * IN_DIM;                    // 256*256
    __hip_bfloat16* wt2a = wt1b + HID * HID;
    __hip_bfloat16* wt2b = wt2a + HID * HID;
    __hip_bfloat16* wt3a = wt2b + HID * HID;
    __hip_bfloat16* wt3b = wt3a + HID * HID;
    float* pooled = (float*)(wt3b + HID * HID);                    // 64*256
    int* deg     = (int*)(pooled + N_GRAPHS * HID);
    int* row_ptr = deg + N_NODES;
    int* pos     = row_ptr + (N_NODES + 1);
    int* col     = pos + N_NODES;                                  // N_EDGES

    float* out = (float*)d_out;

    // ---- prep: weight transpose-convert + CSR build ----
    transpose_to_bf16<<<dim3(8, 4), 256, 0, stream>>>(w1a, wt1a, IN_DIM, HID);
    transpose_to_bf16<<<dim3(8, 8), 256, 0, stream>>>(w1b, wt1b, HID, HID);
    transpose_to_bf16<<<dim3(8, 8), 256, 0, stream>>>(w2a, wt2a, HID, HID);
    transpose_to_bf16<<<dim3(8, 8), 256, 0, stream>>>(w2b, wt2b, HID, HID);
    transpose_to_bf16<<<dim3(8, 8), 256, 0, stream>>>(w3a, wt3a, HID, HID);
    transpose_to_bf16<<<dim3(8, 8), 256, 0, stream>>>(w3b, wt3b, HID, HID);

    zero_int<<<(N_NODES + 255) / 256, 256, 0, stream>>>(deg, N_NODES);
    degree_hist<<<(N_EDGES + 255) / 256, 256, 0, stream>>>(dst, deg, N_EDGES);
    scan_deg<<<1, 1024, 0, stream>>>(deg, row_ptr, pos, N_NODES);
    csr_fill<<<(N_EDGES + 255) / 256, 256, 0, stream>>>(src, dst, pos, col, N_EDGES);

    dim3 ggrid(M_PAD / 128, 2);
    int agg_blocks = (N_NODES + 3) / 4;

    // ---- layer 1 ----
    gin_agg_l1<<<agg_blocks, 256, 0, stream>>>(x, row_ptr, col, bufA);
    gemm_bf16<IN_DIM><<<ggrid, 256, 0, stream>>>(bufA, wt1a, b1a, bufB);
    gemm_bf16<HID><<<ggrid, 256, 0, stream>>>(bufB, wt1b, b1b, bufA);

    // ---- layer 2 ----
    gin_agg_bf16<<<agg_blocks, 256, 0, stream>>>(bufA, row_ptr, col, bufB);
    gemm_bf16<HID><<<ggrid, 256, 0, stream>>>(bufB, wt2a, b2a, bufA);
    gemm_bf16<HID><<<ggrid, 256, 0, stream>>>(bufA, wt2b, b2b, bufB);

    // ---- layer 3 ----
    gin_agg_bf16<<<agg_blocks, 256, 0, stream>>>(bufB, row_ptr, col, bufA);
    gemm_bf16<HID><<<ggrid, 256, 0, stream>>>(bufA, wt3a, b3a, bufB);
    gemm_bf16<HID><<<ggrid, 256, 0, stream>>>(bufB, wt3b, b3b, bufA);

    // ---- pool + head ----
    hipMemsetAsync(pooled, 0, (size_t)N_GRAPHS * HID * sizeof(float), stream);
    pool_partial<<<(N_NODES + 127) / 128, 256, 0, stream>>>(bufA, batch, pooled);
    head_kernel<<<N_GRAPHS, 256, 0, stream>>>(pooled, wl, bl, out);
}

// Round 4
// 274.507 us; speedup vs baseline: 3.6718x; 1.2078x over previous
//
#include <hip/hip_runtime.h>
#include <hip/hip_bf16.h>

#define N_NODES 20000
#define M_PAD 20096            // 157 * 128
#define IN_DIM 128
#define HID 256
#define OUT_DIM 10
#define N_EDGES 320000
#define N_GRAPHS 64

typedef __attribute__((ext_vector_type(8))) short bf16x8;
typedef __attribute__((ext_vector_type(4))) float f32x4;

__device__ inline float bf2f(unsigned short u) {
    return __uint_as_float((unsigned int)u << 16);
}
__device__ inline unsigned short f2bf(float f) {
    __hip_bfloat16 h = __float2bfloat16(f);
    return *reinterpret_cast<unsigned short*>(&h);
}

__device__ __forceinline__ void gl16(const void* g, void* l) {
    __builtin_amdgcn_global_load_lds(
        (const __attribute__((address_space(1))) unsigned int*)g,
        (__attribute__((address_space(3))) unsigned int*)l, 16, 0, 0);
}

// ---------------------------------------------------------------------------
// CSR build
__global__ void zero_int(int* __restrict__ p, int n) {
    int i = blockIdx.x * blockDim.x + threadIdx.x;
    if (i < n) p[i] = 0;
}

__global__ void degree_hist(const int* __restrict__ dst, int* __restrict__ deg, int n) {
    int i = blockIdx.x * blockDim.x + threadIdx.x;
    int stride = gridDim.x * blockDim.x;
    for (; i < n; i += stride) atomicAdd(&deg[dst[i]], 1);
}

__global__ __launch_bounds__(1024) void scan_deg(const int* __restrict__ deg,
                                                 int* __restrict__ row_ptr,
                                                 int* __restrict__ pos, int n) {
    __shared__ int sums[1024];
    int tid = threadIdx.x;
    int chunk = (n + 1023) / 1024;
    int base = tid * chunk;
    int s = 0;
    for (int i = 0; i < chunk; ++i) {
        int idx = base + i;
        if (idx < n) s += deg[idx];
    }
    sums[tid] = s;
    __syncthreads();
    for (int off = 1; off < 1024; off <<= 1) {
        int v = (tid >= off) ? sums[tid - off] : 0;
        __syncthreads();
        if (tid >= off) sums[tid] += v;
        __syncthreads();
    }
    int run = (tid == 0) ? 0 : sums[tid - 1];
    for (int i = 0; i < chunk; ++i) {
        int idx = base + i;
        if (idx < n) {
            row_ptr[idx] = run;
            pos[idx] = run;
            run += deg[idx];
            if (idx == n - 1) row_ptr[n] = run;
        }
    }
}

__global__ void csr_fill(const int* __restrict__ src, const int* __restrict__ dst,
                         int* __restrict__ pos, int* __restrict__ col, int n) {
    int i = blockIdx.x * blockDim.x + threadIdx.x;
    int stride = gridDim.x * blockDim.x;
    for (; i < n; i += stride) {
        int slot = atomicAdd(&pos[dst[i]], 1);
        col[slot] = src[i];
    }
}

// ---------------------------------------------------------------------------
// weight transpose + convert: in[rows][cols] f32 -> out[cols][rows] bf16
__global__ __launch_bounds__(256) void transpose_to_bf16(
    const float* __restrict__ in, __hip_bfloat16* __restrict__ out,
    int rows, int cols)
{
    __shared__ float tile[32][33];
    int c0 = blockIdx.x * 32, r0 = blockIdx.y * 32;
    int tx = threadIdx.x & 31, ty = threadIdx.x >> 5;  // 32 x 8
    for (int i = ty; i < 32; i += 8) {
        int r = r0 + i, c = c0 + tx;
        tile[i][tx] = (r < rows && c < cols) ? in[(size_t)r * cols + c] : 0.f;
    }
    __syncthreads();
    for (int i = ty; i < 32; i += 8) {
        int c = c0 + i, r = r0 + tx;   // write out[c][r]
        if (c < cols && r < rows) out[(size_t)c * rows + r] = __float2bfloat16(tile[tx][i]);
    }
}

// ---------------------------------------------------------------------------
// layer-1 aggregate: f32 in [N_NODES][128] -> bf16 out [M_PAD][128]
// one wave per node, 8-deep unrolled gather for MLP
__global__ __launch_bounds__(256) void gin_agg_l1(
    const float* __restrict__ x, const int* __restrict__ row_ptr,
    const int* __restrict__ col, __hip_bfloat16* __restrict__ out)
{
    int node = blockIdx.x * 4 + (threadIdx.x >> 6);
    if (node >= N_NODES) return;
    int lane = threadIdx.x & 63;
    int off = lane * 2;
    float2 a = *reinterpret_cast<const float2*>(x + (size_t)node * IN_DIM + off);
    float ax = a.x, ay = a.y;
    int s = row_ptr[node], e = row_ptr[node + 1];
    int k = s;
    for (; k + 8 <= e; k += 8) {
        float2 v[8];
        #pragma unroll
        for (int j = 0; j < 8; ++j)
            v[j] = *reinterpret_cast<const float2*>(x + (size_t)col[k + j] * IN_DIM + off);
        #pragma unroll
        for (int j = 0; j < 8; ++j) { ax += v[j].x; ay += v[j].y; }
    }
    for (; k < e; ++k) {
        float2 v = *reinterpret_cast<const float2*>(x + (size_t)col[k] * IN_DIM + off);
        ax += v.x; ay += v.y;
    }
    ushort2 o;
    o.x = f2bf(ax); o.y = f2bf(ay);
    *reinterpret_cast<ushort2*>(out + (size_t)node * IN_DIM + off) = o;
}

// bf16 aggregate: bf16 in [M_PAD][256] -> bf16 out [M_PAD][256]
__global__ __launch_bounds__(256) void gin_agg_bf16(
    const __hip_bfloat16* __restrict__ x, const int* __restrict__ row_ptr,
    const int* __restrict__ col, __hip_bfloat16* __restrict__ out)
{
    int node = blockIdx.x * 4 + (threadIdx.x >> 6);
    if (node >= N_NODES) return;
    int lane = threadIdx.x & 63;
    int off = lane * 4;
    float a0, a1, a2, a3;
    {
        ushort4 v = *reinterpret_cast<const ushort4*>(x + (size_t)node * HID + off);
        a0 = bf2f(v.x); a1 = bf2f(v.y); a2 = bf2f(v.z); a3 = bf2f(v.w);
    }
    int s = row_ptr[node], e = row_ptr[node + 1];
    int k = s;
    for (; k + 8 <= e; k += 8) {
        ushort4 u[8];
        #pragma unroll
        for (int j = 0; j < 8; ++j)
            u[j] = *reinterpret_cast<const ushort4*>(x + (size_t)col[k + j] * HID + off);
        #pragma unroll
        for (int j = 0; j < 8; ++j) {
            a0 += bf2f(u[j].x); a1 += bf2f(u[j].y); a2 += bf2f(u[j].z); a3 += bf2f(u[j].w);
        }
    }
    for (; k < e; ++k) {
        ushort4 u = *reinterpret_cast<const ushort4*>(x + (size_t)col[k] * HID + off);
        a0 += bf2f(u.x); a1 += bf2f(u.y); a2 += bf2f(u.z); a3 += bf2f(u.w);
    }
    ushort4 o;
    o.x = f2bf(a0); o.y = f2bf(a1); o.z = f2bf(a2); o.w = f2bf(a3);
    *reinterpret_cast<ushort4*>(out + (size_t)node * HID + off) = o;
}

// ---------------------------------------------------------------------------
// bf16 MFMA GEMM: C[M_PAD][256] = relu(A[M_PAD][K] @ Wt[256][K]^T + bias)
// 128x128 tile, BK=32, 4 waves (2x2), wave tile 64x64 (4x4 16x16x32 frags).
// 2-phase double-buffered staging via global_load_lds width 16.
// LDS layout [row][chunk] with chunk XOR swizzle (pos stores chunk pos^((r>>1)&3)),
// realized by pre-swizzling the per-lane GLOBAL source address (linear LDS dest).
template<int K>
__global__ __launch_bounds__(256) void gemm_bf16(
    const __hip_bfloat16* __restrict__ A, const __hip_bfloat16* __restrict__ Wt,
    const float* __restrict__ bias, __hip_bfloat16* __restrict__ C)
{
    // [buf][A(8KB) | B(8KB)] x2 buffers = 32 KB
    __shared__ int4 smem4[2048];
    char* smem = (char*)smem4;

    int tid = threadIdx.x;
    int lane = tid & 63;
    int wid = tid >> 6;
    int wr = wid >> 1, wc = wid & 1;
    int m0 = blockIdx.x * 128;
    int n0 = blockIdx.y * 128;

    f32x4 acc[4][4] = {};

    // staging: wave wid fills segments wid and wid+4 (16 rows x 64B each) of A and B
    int rseg = lane >> 2;            // row within segment
    int p = lane & 3;                // 16B chunk position this lane fills
    int r0s = wid * 16 + rseg;       // tile row, segment 0
    int r1s = (wid + 4) * 16 + rseg; // tile row, segment 1
    int c0 = p ^ ((r0s >> 1) & 3);   // source chunk (inverse swizzle = same XOR)
    int c1 = p ^ ((r1s >> 1) & 3);

    const char* gA0 = (const char*)(A + (size_t)(m0 + r0s) * K) + c0 * 16;
    const char* gA1 = (const char*)(A + (size_t)(m0 + r1s) * K) + c1 * 16;
    const char* gB0 = (const char*)(Wt + (size_t)(n0 + r0s) * K) + c0 * 16;
    const char* gB1 = (const char*)(Wt + (size_t)(n0 + r1s) * K) + c1 * 16;

    int ldsA0 = wid * 1024;          // uniform per wave
    int ldsA1 = (wid + 4) * 1024;

    constexpr int NT = K / 32;

    int g = lane >> 4;               // k-group for fragment reads
    int r16 = lane & 15;
    int gg = g ^ ((r16 >> 1) & 3);   // swizzled chunk for fragment reads

    auto stage = [&](int buf, int t) {
        char* l = smem + buf * 16384;
        int tb = t * 64;
        gl16(gA0 + tb, l + ldsA0);
        gl16(gA1 + tb, l + ldsA1);
        gl16(gB0 + tb, l + 8192 + ldsA0);
        gl16(gB1 + tb, l + 8192 + ldsA1);
    };

    stage(0, 0);
    __syncthreads();   // compiler emits vmcnt(0) drain before s_barrier

    #pragma unroll
    for (int t = 0; t < NT; ++t) {
        int cur = t & 1;
        if (t + 1 < NT) stage(cur ^ 1, t + 1);   // prefetch next tile (in flight over compute)

        const char* As = smem + cur * 16384;
        const char* Bs = As + 8192;

        bf16x8 af[4], bfr[4];
        #pragma unroll
        for (int m = 0; m < 4; ++m) {
            int row = wr * 64 + m * 16 + r16;
            af[m] = *reinterpret_cast<const bf16x8*>(As + row * 64 + gg * 16);
        }
        #pragma unroll
        for (int n = 0; n < 4; ++n) {
            int row = wc * 64 + n * 16 + r16;
            bfr[n] = *reinterpret_cast<const bf16x8*>(Bs + row * 64 + gg * 16);
        }
        #pragma unroll
        for (int m = 0; m < 4; ++m)
            #pragma unroll
            for (int n = 0; n < 4; ++n)
                acc[m][n] = __builtin_amdgcn_mfma_f32_16x16x32_bf16(af[m], bfr[n], acc[m][n], 0, 0, 0);

        __syncthreads();   // drains vmcnt (prefetch) + lgkm; protects both buffers
    }

    // epilogue: bias + relu + bf16 store.  C/D: col=lane&15, row=(lane>>4)*4+reg
    float bv[4];
    #pragma unroll
    for (int n = 0; n < 4; ++n) bv[n] = bias[n0 + wc * 64 + n * 16 + r16];

    #pragma unroll
    for (int m = 0; m < 4; ++m) {
        #pragma unroll
        for (int n = 0; n < 4; ++n) {
            int col = n0 + wc * 64 + n * 16 + r16;
            #pragma unroll
            for (int r = 0; r < 4; ++r) {
                int row = m0 + wr * 64 + m * 16 + (lane >> 4) * 4 + r;
                float v = acc[m][n][r] + bv[n];
                v = fmaxf(v, 0.f);
                C[(size_t)row * HID + col] = __float2bfloat16(v);
            }
        }
    }
}

// ---------------------------------------------------------------------------
// pooling: per-block register acc over 128 sorted nodes, atomic flush at
// graph boundaries. pooled must be zeroed first.
__global__ __launch_bounds__(256) void pool_partial(
    const __hip_bfloat16* __restrict__ h, const int* __restrict__ batch,
    float* __restrict__ pooled)
{
    __shared__ int sb[128];
    int n0 = blockIdx.x * 128;
    int cnt = N_NODES - n0; if (cnt > 128) cnt = 128;
    int d = threadIdx.x;
    if (d < cnt) sb[d] = batch[n0 + d];
    __syncthreads();
    float acc = 0.f;
    int cur = sb[0];
    for (int i = 0; i < cnt; ++i) {
        int g = sb[i];
        if (g != cur) { atomicAdd(&pooled[cur * HID + d], acc); acc = 0.f; cur = g; }
        acc += bf2f(*reinterpret_cast<const unsigned short*>(h + (size_t)(n0 + i) * HID + d));
    }
    atomicAdd(&pooled[cur * HID + d], acc);
}

// head: logits = pooled @ wl + bl ; log_softmax
__global__ __launch_bounds__(256) void head_kernel(
    const float* __restrict__ pooled, const float* __restrict__ wl,
    const float* __restrict__ bl, float* __restrict__ out)
{
    int gph = blockIdx.x;
    int d = threadIdx.x;
    __shared__ float p[HID];
    __shared__ float logits[OUT_DIM];
    __shared__ float lse_s;
    p[d] = pooled[gph * HID + d];
    __syncthreads();
    if (d < OUT_DIM) {
        float v = bl[d];
        for (int k = 0; k < HID; ++k) v += p[k] * wl[k * OUT_DIM + d];
        logits[d] = v;
    }
    __syncthreads();
    if (d == 0) {
        float mx = logits[0];
        for (int j = 1; j < OUT_DIM; ++j) mx = fmaxf(mx, logits[j]);
        float s = 0.f;
        for (int j = 0; j < OUT_DIM; ++j) s += expf(logits[j] - mx);
        lse_s = mx + logf(s);
    }
    __syncthreads();
    if (d < OUT_DIM) out[gph * OUT_DIM + d] = logits[d] - lse_s;
}

// ---------------------------------------------------------------------------
extern "C" void kernel_launch(void* const* d_in, const int* in_sizes, int n_in,
                              void* d_out, int out_size, void* d_ws, size_t ws_size,
                              hipStream_t stream) {
    const float* x    = (const float*)d_in[0];
    const int*   ei   = (const int*)d_in[1];
    const int*   batch= (const int*)d_in[2];
    const float* w1a  = (const float*)d_in[3];
    const float* b1a  = (const float*)d_in[4];
    const float* w1b  = (const float*)d_in[5];
    const float* b1b  = (const float*)d_in[6];
    const float* w2a  = (const float*)d_in[7];
    const float* b2a  = (const float*)d_in[8];
    const float* w2b  = (const float*)d_in[9];
    const float* b2b  = (const float*)d_in[10];
    const float* w3a  = (const float*)d_in[11];
    const float* b3a  = (const float*)d_in[12];
    const float* w3b  = (const float*)d_in[13];
    const float* b3b  = (const float*)d_in[14];
    const float* wl   = (const float*)d_in[15];
    const float* bl   = (const float*)d_in[16];

    const int* src = ei;
    const int* dst = ei + N_EDGES;

    __hip_bfloat16* bufA = (__hip_bfloat16*)d_ws;                  // M_PAD*256
    __hip_bfloat16* bufB = bufA + (size_t)M_PAD * HID;             // M_PAD*256
    __hip_bfloat16* wt1a = bufB + (size_t)M_PAD * HID;             // 256*128
    __hip_bfloat16* wt1b = wt1a + HID * IN_DIM;                    // 256*256
    __hip_bfloat16* wt2a = wt1b + HID * HID;
    __hip_bfloat16* wt2b = wt2a + HID * HID;
    __hip_bfloat16* wt3a = wt2b + HID * HID;
    __hip_bfloat16* wt3b = wt3a + HID * HID;
    float* pooled = (float*)(wt3b + HID * HID);                    // 64*256
    int* deg     = (int*)(pooled + N_GRAPHS * HID);
    int* row_ptr = deg + N_NODES;
    int* pos     = row_ptr + (N_NODES + 1);
    int* col     = pos + N_NODES;                                  // N_EDGES

    float* out = (float*)d_out;

    // ---- prep: weight transpose-convert + CSR build ----
    transpose_to_bf16<<<dim3(8, 4), 256, 0, stream>>>(w1a, wt1a, IN_DIM, HID);
    transpose_to_bf16<<<dim3(8, 8), 256, 0, stream>>>(w1b, wt1b, HID, HID);
    transpose_to_bf16<<<dim3(8, 8), 256, 0, stream>>>(w2a, wt2a, HID, HID);
    transpose_to_bf16<<<dim3(8, 8), 256, 0, stream>>>(w2b, wt2b, HID, HID);
    transpose_to_bf16<<<dim3(8, 8), 256, 0, stream>>>(w3a, wt3a, HID, HID);
    transpose_to_bf16<<<dim3(8, 8), 256, 0, stream>>>(w3b, wt3b, HID, HID);

    zero_int<<<(N_NODES + 255) / 256, 256, 0, stream>>>(deg, N_NODES);
    degree_hist<<<(N_EDGES + 255) / 256, 256, 0, stream>>>(dst, deg, N_EDGES);
    scan_deg<<<1, 1024, 0, stream>>>(deg, row_ptr, pos, N_NODES);
    csr_fill<<<(N_EDGES + 255) / 256, 256, 0, stream>>>(src, dst, pos, col, N_EDGES);

    dim3 ggrid(M_PAD / 128, 2);
    int agg_blocks = (N_NODES + 3) / 4;

    // ---- layer 1 ----
    gin_agg_l1<<<agg_blocks, 256, 0, stream>>>(x, row_ptr, col, bufA);
    gemm_bf16<IN_DIM><<<ggrid, 256, 0, stream>>>(bufA, wt1a, b1a, bufB);
    gemm_bf16<HID><<<ggrid, 256, 0, stream>>>(bufB, wt1b, b1b, bufA);

    // ---- layer 2 ----
    gin_agg_bf16<<<agg_blocks, 256, 0, stream>>>(bufA, row_ptr, col, bufB);
    gemm_bf16<HID><<<ggrid, 256, 0, stream>>>(bufB, wt2a, b2a, bufA);
    gemm_bf16<HID><<<ggrid, 256, 0, stream>>>(bufA, wt2b, b2b, bufB);

    // ---- layer 3 ----
    gin_agg_bf16<<<agg_blocks, 256, 0, stream>>>(bufB, row_ptr, col, bufA);
    gemm_bf16<HID><<<ggrid, 256, 0, stream>>>(bufA, wt3a, b3a, bufB);
    gemm_bf16<HID><<<ggrid, 256, 0, stream>>>(bufB, wt3b, b3b, bufA);

    // ---- pool + head ----
    hipMemsetAsync(pooled, 0, (size_t)N_GRAPHS * HID * sizeof(float), stream);
    pool_partial<<<(N_NODES + 127) / 128, 256, 0, stream>>>(bufA, batch, pooled);
    head_kernel<<<N_GRAPHS, 256, 0, stream>>>(pooled, wl, bl, out);
}

// Round 5
// 247.559 us; speedup vs baseline: 4.0715x; 1.1089x over previous
//
#include <hip/hip_runtime.h>
#include <hip/hip_bf16.h>

#define N_NODES 20000
#define M_PAD 20096            // 314 * 64
#define IN_DIM 128
#define HID 256
#define OUT_DIM 10
#define N_EDGES 320000
#define N_GRAPHS 64

typedef __attribute__((ext_vector_type(8))) short bf16x8;
typedef __attribute__((ext_vector_type(4))) float f32x4;

__device__ inline float bf2f(unsigned short u) {
    return __uint_as_float((unsigned int)u << 16);
}
__device__ inline unsigned short f2bf(float f) {
    __hip_bfloat16 h = __float2bfloat16(f);
    return *reinterpret_cast<unsigned short*>(&h);
}

__device__ __forceinline__ void gl16(const void* g, void* l) {
    __builtin_amdgcn_global_load_lds(
        (const __attribute__((address_space(1))) unsigned int*)g,
        (__attribute__((address_space(3))) unsigned int*)l, 16, 0, 0);
}

// ---------------------------------------------------------------------------
// CSR build
__global__ void zero_int(int* __restrict__ p, int n) {
    int i = blockIdx.x * blockDim.x + threadIdx.x;
    if (i < n) p[i] = 0;
}

__global__ void degree_hist(const int* __restrict__ dst, int* __restrict__ deg, int n) {
    int i = blockIdx.x * blockDim.x + threadIdx.x;
    int stride = gridDim.x * blockDim.x;
    for (; i < n; i += stride) atomicAdd(&deg[dst[i]], 1);
}

__global__ __launch_bounds__(1024) void scan_deg(const int* __restrict__ deg,
                                                 int* __restrict__ row_ptr,
                                                 int* __restrict__ pos, int n) {
    __shared__ int sums[1024];
    int tid = threadIdx.x;
    int chunk = (n + 1023) / 1024;
    int base = tid * chunk;
    int s = 0;
    for (int i = 0; i < chunk; ++i) {
        int idx = base + i;
        if (idx < n) s += deg[idx];
    }
    sums[tid] = s;
    __syncthreads();
    for (int off = 1; off < 1024; off <<= 1) {
        int v = (tid >= off) ? sums[tid - off] : 0;
        __syncthreads();
        if (tid >= off) sums[tid] += v;
        __syncthreads();
    }
    int run = (tid == 0) ? 0 : sums[tid - 1];
    for (int i = 0; i < chunk; ++i) {
        int idx = base + i;
        if (idx < n) {
            row_ptr[idx] = run;
            pos[idx] = run;
            run += deg[idx];
            if (idx == n - 1) row_ptr[n] = run;
        }
    }
}

__global__ void csr_fill(const int* __restrict__ src, const int* __restrict__ dst,
                         int* __restrict__ pos, int* __restrict__ col, int n) {
    int i = blockIdx.x * blockDim.x + threadIdx.x;
    int stride = gridDim.x * blockDim.x;
    for (; i < n; i += stride) {
        int slot = atomicAdd(&pos[dst[i]], 1);
        col[slot] = src[i];
    }
}

// ---------------------------------------------------------------------------
// batched weight transpose+convert: 6 matrices, in[rows][256] f32 -> out[256][rows] bf16
__global__ __launch_bounds__(256) void transpose_all(
    const float* __restrict__ w1a, const float* __restrict__ w1b,
    const float* __restrict__ w2a, const float* __restrict__ w2b,
    const float* __restrict__ w3a, const float* __restrict__ w3b,
    __hip_bfloat16* __restrict__ o1a, __hip_bfloat16* __restrict__ o1b,
    __hip_bfloat16* __restrict__ o2a, __hip_bfloat16* __restrict__ o2b,
    __hip_bfloat16* __restrict__ o3a, __hip_bfloat16* __restrict__ o3b)
{
    __shared__ float tile[32][33];
    int z = blockIdx.z;
    const float* in = (z == 0) ? w1a : (z == 1) ? w1b : (z == 2) ? w2a
                    : (z == 3) ? w2b : (z == 4) ? w3a : w3b;
    __hip_bfloat16* out = (z == 0) ? o1a : (z == 1) ? o1b : (z == 2) ? o2a
                        : (z == 3) ? o2b : (z == 4) ? o3a : o3b;
    int rows = (z == 0) ? IN_DIM : HID;
    int r0 = blockIdx.y * 32;
    if (r0 >= rows) return;
    int c0 = blockIdx.x * 32;
    int tx = threadIdx.x & 31, ty = threadIdx.x >> 5;
    for (int i = ty; i < 32; i += 8)
        tile[i][tx] = in[(size_t)(r0 + i) * HID + c0 + tx];
    __syncthreads();
    for (int i = ty; i < 32; i += 8)
        out[(size_t)(c0 + i) * rows + r0 + tx] = __float2bfloat16(tile[tx][i]);
}

// ---------------------------------------------------------------------------
// layer-1 aggregate: f32 in [N_NODES][128] -> bf16 out [M_PAD][128]
__global__ __launch_bounds__(256) void gin_agg_l1(
    const float* __restrict__ x, const int* __restrict__ row_ptr,
    const int* __restrict__ col, __hip_bfloat16* __restrict__ out)
{
    int node = blockIdx.x * 4 + (threadIdx.x >> 6);
    if (node >= N_NODES) return;
    int lane = threadIdx.x & 63;
    int off = lane * 2;
    float2 a = *reinterpret_cast<const float2*>(x + (size_t)node * IN_DIM + off);
    float ax = a.x, ay = a.y;
    int s = row_ptr[node], e = row_ptr[node + 1];
    int k = s;
    for (; k + 8 <= e; k += 8) {
        float2 v[8];
        #pragma unroll
        for (int j = 0; j < 8; ++j)
            v[j] = *reinterpret_cast<const float2*>(x + (size_t)col[k + j] * IN_DIM + off);
        #pragma unroll
        for (int j = 0; j < 8; ++j) { ax += v[j].x; ay += v[j].y; }
    }
    for (; k < e; ++k) {
        float2 v = *reinterpret_cast<const float2*>(x + (size_t)col[k] * IN_DIM + off);
        ax += v.x; ay += v.y;
    }
    ushort2 o;
    o.x = f2bf(ax); o.y = f2bf(ay);
    *reinterpret_cast<ushort2*>(out + (size_t)node * IN_DIM + off) = o;
}

// bf16 aggregate: bf16 in [M_PAD][256] -> bf16 out [M_PAD][256]
__global__ __launch_bounds__(256) void gin_agg_bf16(
    const __hip_bfloat16* __restrict__ x, const int* __restrict__ row_ptr,
    const int* __restrict__ col, __hip_bfloat16* __restrict__ out)
{
    int node = blockIdx.x * 4 + (threadIdx.x >> 6);
    if (node >= N_NODES) return;
    int lane = threadIdx.x & 63;
    int off = lane * 4;
    float a0, a1, a2, a3;
    {
        ushort4 v = *reinterpret_cast<const ushort4*>(x + (size_t)node * HID + off);
        a0 = bf2f(v.x); a1 = bf2f(v.y); a2 = bf2f(v.z); a3 = bf2f(v.w);
    }
    int s = row_ptr[node], e = row_ptr[node + 1];
    int k = s;
    for (; k + 8 <= e; k += 8) {
        ushort4 u[8];
        #pragma unroll
        for (int j = 0; j < 8; ++j)
            u[j] = *reinterpret_cast<const ushort4*>(x + (size_t)col[k + j] * HID + off);
        #pragma unroll
        for (int j = 0; j < 8; ++j) {
            a0 += bf2f(u[j].x); a1 += bf2f(u[j].y); a2 += bf2f(u[j].z); a3 += bf2f(u[j].w);
        }
    }
    for (; k < e; ++k) {
        ushort4 u = *reinterpret_cast<const ushort4*>(x + (size_t)col[k] * HID + off);
        a0 += bf2f(u.x); a1 += bf2f(u.y); a2 += bf2f(u.z); a3 += bf2f(u.w);
    }
    ushort4 o;
    o.x = f2bf(a0); o.y = f2bf(a1); o.z = f2bf(a2); o.w = f2bf(a3);
    *reinterpret_cast<ushort4*>(out + (size_t)node * HID + off) = o;
}

// ---------------------------------------------------------------------------
// fused per-layer MLP: C = relu(relu(A @ W1t^T + b1) @ W2t^T + b2)
// A [M_PAD][K1] bf16, W1t [256][K1] bf16, W2t [256][256] bf16, C [M_PAD][256] bf16
// BM=64, BN=256 (full width, so stage-2 K-reduction is block-local).
// 4 waves; wave w owns cols [w*64, w*64+64).
// LDS: stage region 2x20480 (A chunk 4KB + W1 chunk 16KB per buf; W2 reuses
// as 2x16384), mid 64x512B XOR-swizzled (chunk ^= row&7). Total 72 KB.
template<int K1>
__global__ __launch_bounds__(256) void gin_mlp(
    const __hip_bfloat16* __restrict__ A, const __hip_bfloat16* __restrict__ W1t,
    const float* __restrict__ b1, const __hip_bfloat16* __restrict__ W2t,
    const float* __restrict__ b2, __hip_bfloat16* __restrict__ C)
{
    __shared__ int4 smem4[4608];       // 73728 B
    char* smem = (char*)smem4;
    char* mid = smem + 40960;          // 64 x 512B

    int tid = threadIdx.x;
    int lane = tid & 63;
    int wid = tid >> 6;                // wave -> col slice
    int m0 = blockIdx.x * 64;

    int r16 = lane & 15;
    int g = lane >> 4;
    int gg = g ^ ((r16 >> 1) & 3);     // read-side chunk swizzle (64B-row tiles)

    // staging: lane -> dest row (lane>>2), dest chunk (lane&3);
    // source chunk pre-swizzled so LDS[row][p] holds src chunk p^((row>>1)&3)
    int rseg = lane >> 2;
    int sw = (lane & 3) ^ ((lane >> 3) & 3);
    int rA = wid * 16 + rseg;

    const char* gA = (const char*)A + (size_t)(m0 + rA) * (K1 * 2) + sw * 16;
    const char* gW1[4];
    #pragma unroll
    for (int j = 0; j < 4; ++j) {
        int rW = (wid + 4 * j) * 16 + rseg;
        gW1[j] = (const char*)W1t + (size_t)rW * (K1 * 2) + sw * 16;
    }

    auto stage1 = [&](int buf, int t) {
        char* l = smem + buf * 20480;
        gl16(gA + t * 64, l + wid * 1024);
        #pragma unroll
        for (int j = 0; j < 4; ++j)
            gl16(gW1[j] + t * 64, l + 4096 + (wid + 4 * j) * 1024);
    };

    // ---- stage 1: mid = relu(A @ W1t^T + b1) ----
    f32x4 acc[4][4] = {};
    constexpr int NT1 = K1 / 32;

    stage1(0, 0);
    __syncthreads();
    #pragma unroll
    for (int t = 0; t < NT1; ++t) {
        int cur = t & 1;
        if (t + 1 < NT1) stage1(cur ^ 1, t + 1);
        const char* As = smem + cur * 20480;
        const char* Bs = As + 4096;
        bf16x8 af[4], bfv[4];
        #pragma unroll
        for (int m = 0; m < 4; ++m)
            af[m] = *reinterpret_cast<const bf16x8*>(As + (m * 16 + r16) * 64 + gg * 16);
        #pragma unroll
        for (int n = 0; n < 4; ++n)
            bfv[n] = *reinterpret_cast<const bf16x8*>(Bs + (wid * 64 + n * 16 + r16) * 64 + gg * 16);
        #pragma unroll
        for (int m = 0; m < 4; ++m)
            #pragma unroll
            for (int n = 0; n < 4; ++n)
                acc[m][n] = __builtin_amdgcn_mfma_f32_16x16x32_bf16(af[m], bfv[n], acc[m][n], 0, 0, 0);
        __syncthreads();
    }

    // epilogue 1: bias+relu -> bf16 -> mid (swizzled). C/D: col=lane&15, row=g*4+reg
    #pragma unroll
    for (int m = 0; m < 4; ++m) {
        #pragma unroll
        for (int n = 0; n < 4; ++n) {
            int col = wid * 64 + n * 16 + r16;
            float bb = b1[col];
            int cb = col >> 3;
            int within = (col & 7) * 2;
            #pragma unroll
            for (int r = 0; r < 4; ++r) {
                int row = m * 16 + g * 4 + r;
                float v = fmaxf(acc[m][n][r] + bb, 0.f);
                *reinterpret_cast<unsigned short*>(
                    mid + row * 512 + ((cb ^ (row & 7)) << 4) + within) = f2bf(v);
            }
        }
    }

    // ---- stage 2: C = relu(mid @ W2t^T + b2) ----
    const char* gW2[4];
    #pragma unroll
    for (int j = 0; j < 4; ++j) {
        int rW = (wid + 4 * j) * 16 + rseg;
        gW2[j] = (const char*)W2t + (size_t)rW * 512 + sw * 16;
    }
    auto stageW2 = [&](int buf, int t) {
        char* l = smem + buf * 16384;
        #pragma unroll
        for (int j = 0; j < 4; ++j)
            gl16(gW2[j] + t * 64, l + (wid + 4 * j) * 1024);
    };

    stageW2(0, 0);
    __syncthreads();   // covers mid ds_writes + W2 staging

    f32x4 acc2[4][4] = {};
    #pragma unroll
    for (int t = 0; t < 8; ++t) {
        int cur = t & 1;
        if (t + 1 < 8) stageW2(cur ^ 1, t + 1);
        const char* Bs = smem + cur * 16384;
        bf16x8 af[4], bfv[4];
        #pragma unroll
        for (int m = 0; m < 4; ++m) {
            int row = m * 16 + r16;
            int c = (t * 4 + g) ^ (row & 7);
            af[m] = *reinterpret_cast<const bf16x8*>(mid + row * 512 + c * 16);
        }
        #pragma unroll
        for (int n = 0; n < 4; ++n)
            bfv[n] = *reinterpret_cast<const bf16x8*>(Bs + (wid * 64 + n * 16 + r16) * 64 + gg * 16);
        #pragma unroll
        for (int m = 0; m < 4; ++m)
            #pragma unroll
            for (int n = 0; n < 4; ++n)
                acc2[m][n] = __builtin_amdgcn_mfma_f32_16x16x32_bf16(af[m], bfv[n], acc2[m][n], 0, 0, 0);
        __syncthreads();
    }

    // epilogue 2: bias+relu -> C
    #pragma unroll
    for (int m = 0; m < 4; ++m) {
        #pragma unroll
        for (int n = 0; n < 4; ++n) {
            int col = wid * 64 + n * 16 + r16;
            float bb = b2[col];
            #pragma unroll
            for (int r = 0; r < 4; ++r) {
                int row = m0 + m * 16 + g * 4 + r;
                float v = fmaxf(acc2[m][n][r] + bb, 0.f);
                C[(size_t)row * HID + col] = __float2bfloat16(v);
            }
        }
    }
}

// ---------------------------------------------------------------------------
// pooling: per-block register acc over 128 sorted nodes, atomic flush at
// graph boundaries. pooled zeroed by zero_int.
__global__ __launch_bounds__(256) void pool_partial(
    const __hip_bfloat16* __restrict__ h, const int* __restrict__ batch,
    float* __restrict__ pooled)
{
    __shared__ int sb[128];
    int n0 = blockIdx.x * 128;
    int cnt = N_NODES - n0; if (cnt > 128) cnt = 128;
    int d = threadIdx.x;
    if (d < cnt) sb[d] = batch[n0 + d];
    __syncthreads();
    float acc = 0.f;
    int cur = sb[0];
    for (int i = 0; i < cnt; ++i) {
        int g = sb[i];
        if (g != cur) { atomicAdd(&pooled[cur * HID + d], acc); acc = 0.f; cur = g; }
        acc += bf2f(*reinterpret_cast<const unsigned short*>(h + (size_t)(n0 + i) * HID + d));
    }
    atomicAdd(&pooled[cur * HID + d], acc);
}

// head: logits = pooled @ wl + bl ; log_softmax
__global__ __launch_bounds__(256) void head_kernel(
    const float* __restrict__ pooled, const float* __restrict__ wl,
    const float* __restrict__ bl, float* __restrict__ out)
{
    int gph = blockIdx.x;
    int d = threadIdx.x;
    __shared__ float p[HID];
    __shared__ float logits[OUT_DIM];
    __shared__ float lse_s;
    p[d] = pooled[gph * HID + d];
    __syncthreads();
    if (d < OUT_DIM) {
        float v = bl[d];
        for (int k = 0; k < HID; ++k) v += p[k] * wl[k * OUT_DIM + d];
        logits[d] = v;
    }
    __syncthreads();
    if (d == 0) {
        float mx = logits[0];
        for (int j = 1; j < OUT_DIM; ++j) mx = fmaxf(mx, logits[j]);
        float s = 0.f;
        for (int j = 0; j < OUT_DIM; ++j) s += expf(logits[j] - mx);
        lse_s = mx + logf(s);
    }
    __syncthreads();
    if (d < OUT_DIM) out[gph * OUT_DIM + d] = logits[d] - lse_s;
}

// ---------------------------------------------------------------------------
extern "C" void kernel_launch(void* const* d_in, const int* in_sizes, int n_in,
                              void* d_out, int out_size, void* d_ws, size_t ws_size,
                              hipStream_t stream) {
    const float* x    = (const float*)d_in[0];
    const int*   ei   = (const int*)d_in[1];
    const int*   batch= (const int*)d_in[2];
    const float* w1a  = (const float*)d_in[3];
    const float* b1a  = (const float*)d_in[4];
    const float* w1b  = (const float*)d_in[5];
    const float* b1b  = (const float*)d_in[6];
    const float* w2a  = (const float*)d_in[7];
    const float* b2a  = (const float*)d_in[8];
    const float* w2b  = (const float*)d_in[9];
    const float* b2b  = (const float*)d_in[10];
    const float* w3a  = (const float*)d_in[11];
    const float* b3a  = (const float*)d_in[12];
    const float* w3b  = (const float*)d_in[13];
    const float* b3b  = (const float*)d_in[14];
    const float* wl   = (const float*)d_in[15];
    const float* bl   = (const float*)d_in[16];

    const int* src = ei;
    const int* dst = ei + N_EDGES;

    __hip_bfloat16* bufA = (__hip_bfloat16*)d_ws;                  // M_PAD*256
    __hip_bfloat16* bufB = bufA + (size_t)M_PAD * HID;             // M_PAD*256
    __hip_bfloat16* wt1a = bufB + (size_t)M_PAD * HID;             // 256*128
    __hip_bfloat16* wt1b = wt1a + HID * IN_DIM;                    // 256*256
    __hip_bfloat16* wt2a = wt1b + HID * HID;
    __hip_bfloat16* wt2b = wt2a + HID * HID;
    __hip_bfloat16* wt3a = wt2b + HID * HID;
    __hip_bfloat16* wt3b = wt3a + HID * HID;
    float* pooled = (float*)(wt3b + HID * HID);                    // 64*256
    int* deg     = (int*)(pooled + N_GRAPHS * HID);                // contiguous w/ pooled
    int* row_ptr = deg + N_NODES;
    int* pos     = row_ptr + (N_NODES + 1);
    int* col     = pos + N_NODES;                                  // N_EDGES

    float* out = (float*)d_out;

    // ---- prep: batched weight transpose + CSR build (+ zero pooled) ----
    transpose_all<<<dim3(8, 8, 6), 256, 0, stream>>>(
        w1a, w1b, w2a, w2b, w3a, w3b, wt1a, wt1b, wt2a, wt2b, wt3a, wt3b);

    int zn = N_GRAPHS * HID + N_NODES;   // pooled (as int zeros) + deg
    zero_int<<<(zn + 255) / 256, 256, 0, stream>>>((int*)pooled, zn);
    degree_hist<<<(N_EDGES + 255) / 256, 256, 0, stream>>>(dst, deg, N_EDGES);
    scan_deg<<<1, 1024, 0, stream>>>(deg, row_ptr, pos, N_NODES);
    csr_fill<<<(N_EDGES + 255) / 256, 256, 0, stream>>>(src, dst, pos, col, N_EDGES);

    int agg_blocks = (N_NODES + 3) / 4;
    int mlp_blocks = M_PAD / 64;

    // ---- layer 1 ----
    gin_agg_l1<<<agg_blocks, 256, 0, stream>>>(x, row_ptr, col, bufA);
    gin_mlp<IN_DIM><<<mlp_blocks, 256, 0, stream>>>(bufA, wt1a, b1a, wt1b, b1b, bufB);

    // ---- layer 2 ----
    gin_agg_bf16<<<agg_blocks, 256, 0, stream>>>(bufB, row_ptr, col, bufA);
    gin_mlp<HID><<<mlp_blocks, 256, 0, stream>>>(bufA, wt2a, b2a, wt2b, b2b, bufB);

    // ---- layer 3 ----
    gin_agg_bf16<<<agg_blocks, 256, 0, stream>>>(bufB, row_ptr, col, bufA);
    gin_mlp<HID><<<mlp_blocks, 256, 0, stream>>>(bufA, wt3a, b3a, wt3b, b3b, bufB);

    // ---- pool + head ----
    pool_partial<<<(N_NODES + 127) / 128, 256, 0, stream>>>(bufB, batch, pooled);
    head_kernel<<<N_GRAPHS, 256, 0, stream>>>(pooled, wl, bl, out);
}

// Round 6
// 244.941 us; speedup vs baseline: 4.1150x; 1.0107x over previous
//
#include <hip/hip_runtime.h>
#include <hip/hip_bf16.h>

#define N_NODES 20000
#define M_PAD 20096            // 314 * 64
#define IN_DIM 128
#define HID 256
#define OUT_DIM 10
#define N_EDGES 320000
#define N_GRAPHS 64

typedef __attribute__((ext_vector_type(8))) short bf16x8;
typedef __attribute__((ext_vector_type(4))) float f32x4;

__device__ inline float bf2f(unsigned short u) {
    return __uint_as_float((unsigned int)u << 16);
}
__device__ inline unsigned short f2bf(float f) {
    __hip_bfloat16 h = __float2bfloat16(f);
    return *reinterpret_cast<unsigned short*>(&h);
}

__device__ __forceinline__ void gl16(const void* g, void* l) {
    __builtin_amdgcn_global_load_lds(
        (const __attribute__((address_space(1))) unsigned int*)g,
        (__attribute__((address_space(3))) unsigned int*)l, 16, 0, 0);
}

template<int N> __device__ __forceinline__ void vmwait() {
    asm volatile("s_waitcnt vmcnt(%0)" :: "n"(N) : "memory");
    __builtin_amdgcn_sched_barrier(0);
}

// ---------------------------------------------------------------------------
// CSR build
__global__ void degree_hist(const int* __restrict__ dst, int* __restrict__ deg, int n) {
    int i = blockIdx.x * blockDim.x + threadIdx.x;
    int stride = gridDim.x * blockDim.x;
    for (; i < n; i += stride) atomicAdd(&deg[dst[i]], 1);
}

__global__ __launch_bounds__(1024) void scan_deg(const int* __restrict__ deg,
                                                 int* __restrict__ row_ptr,
                                                 int* __restrict__ pos, int n) {
    __shared__ int sums[1024];
    int tid = threadIdx.x;
    int chunk = (n + 1023) / 1024;
    int base = tid * chunk;
    int s = 0;
    for (int i = 0; i < chunk; ++i) {
        int idx = base + i;
        if (idx < n) s += deg[idx];
    }
    sums[tid] = s;
    __syncthreads();
    for (int off = 1; off < 1024; off <<= 1) {
        int v = (tid >= off) ? sums[tid - off] : 0;
        __syncthreads();
        if (tid >= off) sums[tid] += v;
        __syncthreads();
    }
    int run = (tid == 0) ? 0 : sums[tid - 1];
    for (int i = 0; i < chunk; ++i) {
        int idx = base + i;
        if (idx < n) {
            row_ptr[idx] = run;
            pos[idx] = run;
            run += deg[idx];
            if (idx == n - 1) row_ptr[n] = run;
        }
    }
}

__global__ void csr_fill(const int* __restrict__ src, const int* __restrict__ dst,
                         int* __restrict__ pos, int* __restrict__ col, int n) {
    int i = blockIdx.x * blockDim.x + threadIdx.x;
    int stride = gridDim.x * blockDim.x;
    for (; i < n; i += stride) {
        int slot = atomicAdd(&pos[dst[i]], 1);
        col[slot] = src[i];
    }
}

// ---------------------------------------------------------------------------
// x -> bf16 conversion (layer-1 gather bytes halved)
__global__ void x_to_bf16(const float* __restrict__ x, __hip_bfloat16* __restrict__ o, int n4) {
    int i = blockIdx.x * blockDim.x + threadIdx.x;
    if (i >= n4) return;
    float4 v = reinterpret_cast<const float4*>(x)[i];
    ushort4 u;
    u.x = f2bf(v.x); u.y = f2bf(v.y); u.z = f2bf(v.z); u.w = f2bf(v.w);
    reinterpret_cast<ushort4*>(o)[i] = u;
}

// ---------------------------------------------------------------------------
// batched weight transpose+convert (z<6) + workspace zeroing (z==6)
__global__ __launch_bounds__(256) void transpose_all(
    const float* __restrict__ w1a, const float* __restrict__ w1b,
    const float* __restrict__ w2a, const float* __restrict__ w2b,
    const float* __restrict__ w3a, const float* __restrict__ w3b,
    __hip_bfloat16* __restrict__ o1a, __hip_bfloat16* __restrict__ o1b,
    __hip_bfloat16* __restrict__ o2a, __hip_bfloat16* __restrict__ o2b,
    __hip_bfloat16* __restrict__ o3a, __hip_bfloat16* __restrict__ o3b,
    int* __restrict__ zp, int zn)
{
    __shared__ float tile[32][33];
    int z = blockIdx.z;
    if (z == 6) {
        int i = (blockIdx.y * 8 + blockIdx.x) * 256 + threadIdx.x;
        for (; i < zn; i += 64 * 256) zp[i] = 0;
        return;
    }
    const float* in = (z == 0) ? w1a : (z == 1) ? w1b : (z == 2) ? w2a
                    : (z == 3) ? w2b : (z == 4) ? w3a : w3b;
    __hip_bfloat16* out = (z == 0) ? o1a : (z == 1) ? o1b : (z == 2) ? o2a
                        : (z == 3) ? o2b : (z == 4) ? o3a : o3b;
    int rows = (z == 0) ? IN_DIM : HID;
    int r0 = blockIdx.y * 32;
    if (r0 >= rows) return;
    int c0 = blockIdx.x * 32;
    int tx = threadIdx.x & 31, ty = threadIdx.x >> 5;
    for (int i = ty; i < 32; i += 8)
        tile[i][tx] = in[(size_t)(r0 + i) * HID + c0 + tx];
    __syncthreads();
    for (int i = ty; i < 32; i += 8)
        out[(size_t)(c0 + i) * rows + r0 + tx] = __float2bfloat16(tile[tx][i]);
}

// ---------------------------------------------------------------------------
// bf16 gather-aggregate: out[i] = x[i] + sum_{j in in-edges(i)} x[j]
// one wave per node, 8-deep unrolled gather for MLP
template<int D>
__global__ __launch_bounds__(256) void gin_agg(
    const __hip_bfloat16* __restrict__ x, const int* __restrict__ row_ptr,
    const int* __restrict__ col, __hip_bfloat16* __restrict__ out)
{
    constexpr int PER = D / 64;   // 2 (D=128) or 4 (D=256)
    int node = blockIdx.x * 4 + (threadIdx.x >> 6);
    if (node >= N_NODES) return;
    int lane = threadIdx.x & 63;
    int off = lane * PER;
    float acc[PER];
    if constexpr (PER == 4) {
        ushort4 v = *reinterpret_cast<const ushort4*>(x + (size_t)node * D + off);
        acc[0] = bf2f(v.x); acc[1] = bf2f(v.y); acc[2] = bf2f(v.z); acc[3] = bf2f(v.w);
    } else {
        ushort2 v = *reinterpret_cast<const ushort2*>(x + (size_t)node * D + off);
        acc[0] = bf2f(v.x); acc[1] = bf2f(v.y);
    }
    int s = row_ptr[node], e = row_ptr[node + 1];
    int k = s;
    if constexpr (PER == 4) {
        for (; k + 8 <= e; k += 8) {
            ushort4 u[8];
            #pragma unroll
            for (int j = 0; j < 8; ++j)
                u[j] = *reinterpret_cast<const ushort4*>(x + (size_t)col[k + j] * D + off);
            #pragma unroll
            for (int j = 0; j < 8; ++j) {
                acc[0] += bf2f(u[j].x); acc[1] += bf2f(u[j].y);
                acc[2] += bf2f(u[j].z); acc[3] += bf2f(u[j].w);
            }
        }
        for (; k < e; ++k) {
            ushort4 u = *reinterpret_cast<const ushort4*>(x + (size_t)col[k] * D + off);
            acc[0] += bf2f(u.x); acc[1] += bf2f(u.y); acc[2] += bf2f(u.z); acc[3] += bf2f(u.w);
        }
        ushort4 o;
        o.x = f2bf(acc[0]); o.y = f2bf(acc[1]); o.z = f2bf(acc[2]); o.w = f2bf(acc[3]);
        *reinterpret_cast<ushort4*>(out + (size_t)node * D + off) = o;
    } else {
        for (; k + 8 <= e; k += 8) {
            ushort2 u[8];
            #pragma unroll
            for (int j = 0; j < 8; ++j)
                u[j] = *reinterpret_cast<const ushort2*>(x + (size_t)col[k + j] * D + off);
            #pragma unroll
            for (int j = 0; j < 8; ++j) { acc[0] += bf2f(u[j].x); acc[1] += bf2f(u[j].y); }
        }
        for (; k < e; ++k) {
            ushort2 u = *reinterpret_cast<const ushort2*>(x + (size_t)col[k] * D + off);
            acc[0] += bf2f(u.x); acc[1] += bf2f(u.y);
        }
        ushort2 o;
        o.x = f2bf(acc[0]); o.y = f2bf(acc[1]);
        *reinterpret_cast<ushort2*>(out + (size_t)node * D + off) = o;
    }
}

// ---------------------------------------------------------------------------
// fused per-layer MLP: C = relu(relu(A @ W1t^T + b1) @ W2t^T + b2)
// BM=64, BN=256; 4 waves; counted-vmcnt double-buffered gload_lds staging.
template<int K1>
__global__ __launch_bounds__(256) void gin_mlp(
    const __hip_bfloat16* __restrict__ A, const __hip_bfloat16* __restrict__ W1t,
    const float* __restrict__ b1, const __hip_bfloat16* __restrict__ W2t,
    const float* __restrict__ b2, __hip_bfloat16* __restrict__ C)
{
    __shared__ int4 smem4[4608];       // 73728 B
    char* smem = (char*)smem4;
    char* mid = smem + 40960;          // 64 x 512B

    int tid = threadIdx.x;
    int lane = tid & 63;
    int wid = tid >> 6;                // wave -> col slice
    int m0 = blockIdx.x * 64;

    int r16 = lane & 15;
    int g = lane >> 4;
    int gg = g ^ ((r16 >> 1) & 3);     // read-side chunk swizzle (64B-row tiles)

    // staging: lane -> dest row (lane>>2), dest chunk (lane&3);
    // source chunk pre-swizzled so LDS[row][p] holds src chunk p^((row>>1)&3)
    int rseg = lane >> 2;
    int sw = (lane & 3) ^ ((lane >> 3) & 3);
    int rA = wid * 16 + rseg;

    const char* gA = (const char*)A + (size_t)(m0 + rA) * (K1 * 2) + sw * 16;
    const char* gW1[4];
    #pragma unroll
    for (int j = 0; j < 4; ++j) {
        int rW = (wid + 4 * j) * 16 + rseg;
        gW1[j] = (const char*)W1t + (size_t)rW * (K1 * 2) + sw * 16;
    }

    auto stage1 = [&](int buf, int t) {
        char* l = smem + buf * 20480;
        gl16(gA + t * 64, l + wid * 1024);
        #pragma unroll
        for (int j = 0; j < 4; ++j)
            gl16(gW1[j] + t * 64, l + 4096 + (wid + 4 * j) * 1024);
    };

    // ---- stage 1: mid = relu(A @ W1t^T + b1) ----
    f32x4 acc[4][4] = {};
    constexpr int NT1 = K1 / 32;

    stage1(0, 0);
    #pragma unroll
    for (int t = 0; t < NT1; ++t) {
        int cur = t & 1;
        if (t + 1 < NT1) { stage1(cur ^ 1, t + 1); vmwait<5>(); }
        else             { vmwait<0>(); }
        __builtin_amdgcn_s_barrier();       // all waves: tile t staged
        __builtin_amdgcn_sched_barrier(0);
        const char* As = smem + cur * 20480;
        const char* Bs = As + 4096;
        bf16x8 af[4], bfv[4];
        #pragma unroll
        for (int m = 0; m < 4; ++m)
            af[m] = *reinterpret_cast<const bf16x8*>(As + (m * 16 + r16) * 64 + gg * 16);
        #pragma unroll
        for (int n = 0; n < 4; ++n)
            bfv[n] = *reinterpret_cast<const bf16x8*>(Bs + (wid * 64 + n * 16 + r16) * 64 + gg * 16);
        __builtin_amdgcn_s_setprio(1);
        #pragma unroll
        for (int m = 0; m < 4; ++m)
            #pragma unroll
            for (int n = 0; n < 4; ++n)
                acc[m][n] = __builtin_amdgcn_mfma_f32_16x16x32_bf16(af[m], bfv[n], acc[m][n], 0, 0, 0);
        __builtin_amdgcn_s_setprio(0);
        __builtin_amdgcn_sched_barrier(0);
        __builtin_amdgcn_s_barrier();       // all waves done reading buf cur
        __builtin_amdgcn_sched_barrier(0);
    }

    // ---- issue W2 tile 0 early (latency hides under epilogue-1) ----
    const char* gW2[4];
    #pragma unroll
    for (int j = 0; j < 4; ++j) {
        int rW = (wid + 4 * j) * 16 + rseg;
        gW2[j] = (const char*)W2t + (size_t)rW * 512 + sw * 16;
    }
    auto stageW2 = [&](int buf, int t) {
        char* l = smem + buf * 16384;
        #pragma unroll
        for (int j = 0; j < 4; ++j)
            gl16(gW2[j] + t * 64, l + (wid + 4 * j) * 1024);
    };
    stageW2(0, 0);

    // epilogue 1: bias+relu -> bf16 -> mid (swizzled). C/D: col=lane&15, row=g*4+reg
    #pragma unroll
    for (int m = 0; m < 4; ++m) {
        #pragma unroll
        for (int n = 0; n < 4; ++n) {
            int col = wid * 64 + n * 16 + r16;
            float bb = b1[col];
            int cb = col >> 3;
            int within = (col & 7) * 2;
            #pragma unroll
            for (int r = 0; r < 4; ++r) {
                int row = m * 16 + g * 4 + r;
                float v = fmaxf(acc[m][n][r] + bb, 0.f);
                *reinterpret_cast<unsigned short*>(
                    mid + row * 512 + ((cb ^ (row & 7)) << 4) + within) = f2bf(v);
            }
        }
    }

    __syncthreads();   // drains vmcnt(0)+lgkm(0): W2 tile0 ready, mid visible

    // ---- stage 2: C = relu(mid @ W2t^T + b2) ----
    f32x4 acc2[4][4] = {};
    #pragma unroll
    for (int t = 0; t < 8; ++t) {
        int cur = t & 1;
        if (t + 1 < 8) { stageW2(cur ^ 1, t + 1); vmwait<4>(); }
        else           { vmwait<0>(); }
        __builtin_amdgcn_s_barrier();
        __builtin_amdgcn_sched_barrier(0);
        const char* Bs = smem + cur * 16384;
        bf16x8 af[4], bfv[4];
        #pragma unroll
        for (int m = 0; m < 4; ++m) {
            int row = m * 16 + r16;
            int c = (t * 4 + g) ^ (row & 7);
            af[m] = *reinterpret_cast<const bf16x8*>(mid + row * 512 + c * 16);
        }
        #pragma unroll
        for (int n = 0; n < 4; ++n)
            bfv[n] = *reinterpret_cast<const bf16x8*>(Bs + (wid * 64 + n * 16 + r16) * 64 + gg * 16);
        __builtin_amdgcn_s_setprio(1);
        #pragma unroll
        for (int m = 0; m < 4; ++m)
            #pragma unroll
            for (int n = 0; n < 4; ++n)
                acc2[m][n] = __builtin_amdgcn_mfma_f32_16x16x32_bf16(af[m], bfv[n], acc2[m][n], 0, 0, 0);
        __builtin_amdgcn_s_setprio(0);
        __builtin_amdgcn_sched_barrier(0);
        __builtin_amdgcn_s_barrier();
        __builtin_amdgcn_sched_barrier(0);
    }

    // epilogue 2: bias+relu -> C
    #pragma unroll
    for (int m = 0; m < 4; ++m) {
        #pragma unroll
        for (int n = 0; n < 4; ++n) {
            int col = wid * 64 + n * 16 + r16;
            float bb = b2[col];
            #pragma unroll
            for (int r = 0; r < 4; ++r) {
                int row = m0 + m * 16 + g * 4 + r;
                float v = fmaxf(acc2[m][n][r] + bb, 0.f);
                C[(size_t)row * HID + col] = __float2bfloat16(v);
            }
        }
    }
}

// ---------------------------------------------------------------------------
// pooling: per-block register acc over 128 sorted nodes, atomic flush at
// graph boundaries. pooled zeroed by transpose_all z=6.
__global__ __launch_bounds__(256) void pool_partial(
    const __hip_bfloat16* __restrict__ h, const int* __restrict__ batch,
    float* __restrict__ pooled)
{
    __shared__ int sb[128];
    int n0 = blockIdx.x * 128;
    int cnt = N_NODES - n0; if (cnt > 128) cnt = 128;
    int d = threadIdx.x;
    if (d < cnt) sb[d] = batch[n0 + d];
    __syncthreads();
    float acc = 0.f;
    int cur = sb[0];
    for (int i = 0; i < cnt; ++i) {
        int g = sb[i];
        if (g != cur) { atomicAdd(&pooled[cur * HID + d], acc); acc = 0.f; cur = g; }
        acc += bf2f(*reinterpret_cast<const unsigned short*>(h + (size_t)(n0 + i) * HID + d));
    }
    atomicAdd(&pooled[cur * HID + d], acc);
}

// head: logits = pooled @ wl + bl ; log_softmax
__global__ __launch_bounds__(256) void head_kernel(
    const float* __restrict__ pooled, const float* __restrict__ wl,
    const float* __restrict__ bl, float* __restrict__ out)
{
    int gph = blockIdx.x;
    int d = threadIdx.x;
    __shared__ float p[HID];
    __shared__ float logits[OUT_DIM];
    __shared__ float lse_s;
    p[d] = pooled[gph * HID + d];
    __syncthreads();
    if (d < OUT_DIM) {
        float v = bl[d];
        for (int k = 0; k < HID; ++k) v += p[k] * wl[k * OUT_DIM + d];
        logits[d] = v;
    }
    __syncthreads();
    if (d == 0) {
        float mx = logits[0];
        for (int j = 1; j < OUT_DIM; ++j) mx = fmaxf(mx, logits[j]);
        float s = 0.f;
        for (int j = 0; j < OUT_DIM; ++j) s += expf(logits[j] - mx);
        lse_s = mx + logf(s);
    }
    __syncthreads();
    if (d < OUT_DIM) out[gph * OUT_DIM + d] = logits[d] - lse_s;
}

// ---------------------------------------------------------------------------
extern "C" void kernel_launch(void* const* d_in, const int* in_sizes, int n_in,
                              void* d_out, int out_size, void* d_ws, size_t ws_size,
                              hipStream_t stream) {
    const float* x    = (const float*)d_in[0];
    const int*   ei   = (const int*)d_in[1];
    const int*   batch= (const int*)d_in[2];
    const float* w1a  = (const float*)d_in[3];
    const float* b1a  = (const float*)d_in[4];
    const float* w1b  = (const float*)d_in[5];
    const float* b1b  = (const float*)d_in[6];
    const float* w2a  = (const float*)d_in[7];
    const float* b2a  = (const float*)d_in[8];
    const float* w2b  = (const float*)d_in[9];
    const float* b2b  = (const float*)d_in[10];
    const float* w3a  = (const float*)d_in[11];
    const float* b3a  = (const float*)d_in[12];
    const float* w3b  = (const float*)d_in[13];
    const float* b3b  = (const float*)d_in[14];
    const float* wl   = (const float*)d_in[15];
    const float* bl   = (const float*)d_in[16];

    const int* src = ei;
    const int* dst = ei + N_EDGES;

    __hip_bfloat16* bufA = (__hip_bfloat16*)d_ws;                  // M_PAD*256
    __hip_bfloat16* bufB = bufA + (size_t)M_PAD * HID;             // M_PAD*256
    __hip_bfloat16* x_bf = bufB + (size_t)M_PAD * HID;             // N_NODES*128
    __hip_bfloat16* wt1a = x_bf + (size_t)N_NODES * IN_DIM;        // 256*128
    __hip_bfloat16* wt1b = wt1a + HID * IN_DIM;                    // 256*256
    __hip_bfloat16* wt2a = wt1b + HID * HID;
    __hip_bfloat16* wt2b = wt2a + HID * HID;
    __hip_bfloat16* wt3a = wt2b + HID * HID;
    __hip_bfloat16* wt3b = wt3a + HID * HID;
    float* pooled = (float*)(wt3b + HID * HID);                    // 64*256
    int* deg     = (int*)(pooled + N_GRAPHS * HID);                // contiguous w/ pooled
    int* row_ptr = deg + N_NODES;
    int* pos     = row_ptr + (N_NODES + 1);
    int* col     = pos + N_NODES;                                  // N_EDGES

    float* out = (float*)d_out;

    // ---- prep: transpose weights + zero pooled/deg (z=6), x->bf16, CSR ----
    int zn = N_GRAPHS * HID + N_NODES;
    transpose_all<<<dim3(8, 8, 7), 256, 0, stream>>>(
        w1a, w1b, w2a, w2b, w3a, w3b, wt1a, wt1b, wt2a, wt2b, wt3a, wt3b,
        (int*)pooled, zn);

    int n4 = N_NODES * IN_DIM / 4;
    x_to_bf16<<<(n4 + 255) / 256, 256, 0, stream>>>(x, x_bf, n4);

    degree_hist<<<(N_EDGES + 255) / 256, 256, 0, stream>>>(dst, deg, N_EDGES);
    scan_deg<<<1, 1024, 0, stream>>>(deg, row_ptr, pos, N_NODES);
    csr_fill<<<(N_EDGES + 255) / 256, 256, 0, stream>>>(src, dst, pos, col, N_EDGES);

    int agg_blocks = (N_NODES + 3) / 4;
    int mlp_blocks = M_PAD / 64;

    // ---- layer 1 ----
    gin_agg<IN_DIM><<<agg_blocks, 256, 0, stream>>>(x_bf, row_ptr, col, bufA);
    gin_mlp<IN_DIM><<<mlp_blocks, 256, 0, stream>>>(bufA, wt1a, b1a, wt1b, b1b, bufB);

    // ---- layer 2 ----
    gin_agg<HID><<<agg_blocks, 256, 0, stream>>>(bufB, row_ptr, col, bufA);
    gin_mlp<HID><<<mlp_blocks, 256, 0, stream>>>(bufA, wt2a, b2a, wt2b, b2b, bufB);

    // ---- layer 3 ----
    gin_agg<HID><<<agg_blocks, 256, 0, stream>>>(bufB, row_ptr, col, bufA);
    gin_mlp<HID><<<mlp_blocks, 256, 0, stream>>>(bufA, wt3a, b3a, wt3b, b3b, bufB);

    // ---- pool + head ----
    pool_partial<<<(N_NODES + 127) / 128, 256, 0, stream>>>(bufB, batch, pooled);
    head_kernel<<<N_GRAPHS, 256, 0, stream>>>(pooled, wl, bl, out);
}